// Round 1
// baseline (962.761 us; speedup 1.0000x reference)
//
#include <hip/hip_runtime.h>

// MHA forward, fp32 correctness-first baseline.
// B=2, S=2048, D=1024, H=16, DH=64, scale = 1024^-0.5 = 1/32.
// Pipeline:
//   1) gemm_f32<0>: qkv projections, scatter to [b,h,s,d] (grid.z selects W)
//   2) attn_f32   : causal flash attention, 1-wave blocks, writes [b,s,h*64+d]
//   3) gemm_f32<1>: @ Wo -> d_out
// ws layout (floats): q[4M] k[4M] v[4M] attn[4M] = 64 MB total.

#define S_LEN 2048
#define NH 16
#define DHEAD 64
#define SCALE 0.03125f

// ---------------------------------------------------------------- GEMM ----
// C[4096x1024] = X[4096x1024] @ W[1024x1024]
// MODE 0: head-scatter write  out[((b*16+h)*2048+s)*64 + d]
// MODE 1: flat write          out[m*1024 + n]
template <int MODE>
__global__ __launch_bounds__(256, 2) void gemm_f32(
    const float* __restrict__ X,
    const float* __restrict__ Wa, const float* __restrict__ Wb,
    const float* __restrict__ Wc,
    float* __restrict__ Oa, float* __restrict__ Ob, float* __restrict__ Oc) {
  const int z = blockIdx.z;
  const float* __restrict__ Wp = (z == 0) ? Wa : (z == 1) ? Wb : Wc;
  float* __restrict__ Op = (z == 0) ? Oa : (z == 1) ? Ob : Oc;

  __shared__ float Xs[16][132];  // [k][m] transposed, +4 pad (b128-aligned rows)
  __shared__ float Ws[16][128];  // [k][n]

  const int tid = threadIdx.x;
  const int bm = blockIdx.x;  // 0..31
  const int bn = blockIdx.y;  // 0..7
  const int tx = tid & 15;    // n-group
  const int ty = tid >> 4;    // m-group

  float acc[8][8];
#pragma unroll
  for (int i = 0; i < 8; ++i)
#pragma unroll
    for (int j = 0; j < 8; ++j) acc[i][j] = 0.0f;

  for (int kc = 0; kc < 1024; kc += 16) {
    __syncthreads();
#pragma unroll
    for (int p = 0; p < 2; ++p) {
      const int idx = p * 256 + tid;
      // X tile: 128 rows x 16 k
      const int r = idx >> 2, c4 = idx & 3;
      float4 xv = *(const float4*)&X[(size_t)(bm * 128 + r) * 1024 + kc + c4 * 4];
      Xs[c4 * 4 + 0][r] = xv.x;
      Xs[c4 * 4 + 1][r] = xv.y;
      Xs[c4 * 4 + 2][r] = xv.z;
      Xs[c4 * 4 + 3][r] = xv.w;
      // W tile: 16 k x 128 n
      const int r2 = idx >> 5, c42 = idx & 31;
      float4 wv = *(const float4*)&Wp[(size_t)(kc + r2) * 1024 + bn * 128 + c42 * 4];
      *(float4*)&Ws[r2][c42 * 4] = wv;
    }
    __syncthreads();

#pragma unroll
    for (int kk = 0; kk < 16; ++kk) {
      float4 a0 = *(const float4*)&Xs[kk][ty * 4];
      float4 a1 = *(const float4*)&Xs[kk][ty * 4 + 64];
      float4 b0 = *(const float4*)&Ws[kk][tx * 4];
      float4 b1 = *(const float4*)&Ws[kk][tx * 4 + 64];
      float av[8] = {a0.x, a0.y, a0.z, a0.w, a1.x, a1.y, a1.z, a1.w};
      float bv[8] = {b0.x, b0.y, b0.z, b0.w, b1.x, b1.y, b1.z, b1.w};
#pragma unroll
      for (int i = 0; i < 8; ++i)
#pragma unroll
        for (int j = 0; j < 8; ++j) acc[i][j] = fmaf(av[i], bv[j], acc[i][j]);
    }
  }

  // epilogue
#pragma unroll
  for (int i = 0; i < 8; ++i) {
    const int m = bm * 128 + ((i < 4) ? (ty * 4 + i) : (64 + ty * 4 + i - 4));
#pragma unroll
    for (int jj = 0; jj < 2; ++jj) {
      const int n = bn * 128 + tx * 4 + jj * 64;
      float4 o = make_float4(acc[i][jj * 4 + 0], acc[i][jj * 4 + 1],
                             acc[i][jj * 4 + 2], acc[i][jj * 4 + 3]);
      if constexpr (MODE == 0) {
        const int b = m >> 11, s = m & 2047;  // S=2048
        const int h = n >> 6, d = n & 63;
        *(float4*)&Op[((size_t)(b * NH + h) * S_LEN + s) * DHEAD + d] = o;
      } else {
        *(float4*)&Op[(size_t)m * 1024 + n] = o;
      }
    }
  }
}

// ----------------------------------------------------------- attention ----
// One wave (64 threads) per (q-tile of 64, b*h). KV tiles of 32.
// Q,K,V in [b,h,s,d] (d contiguous, 64). Output flat [b,s,h*64+d].
__global__ __launch_bounds__(64) void attn_f32(const float* __restrict__ Q,
                                               const float* __restrict__ K,
                                               const float* __restrict__ V,
                                               float* __restrict__ O) {
  __shared__ float Qt[64][64];  // [d][q], pre-scaled by 1/32
  __shared__ float Kt[64][32];  // [d][k]
  __shared__ float Vs[32][64];  // [k][d]
  __shared__ float Pm[64][32];  // [q][k ^ ((q>>3)*4)]

  const int lane = threadIdx.x;
  const int lx = lane & 7;
  const int ly = lane >> 3;
  const int q0 = blockIdx.x * 64;
  const int bh = blockIdx.y;
  const size_t base = (size_t)bh * S_LEN * DHEAD;

  // stage Q tile transposed, pre-scaled (uncoalesced but one-time; L1 reuse)
#pragma unroll 4
  for (int p = 0; p < 16; ++p) {
    float4 qv = *(const float4*)&Q[base + (size_t)(q0 + lane) * 64 + p * 4];
    Qt[p * 4 + 0][lane] = qv.x * SCALE;
    Qt[p * 4 + 1][lane] = qv.y * SCALE;
    Qt[p * 4 + 2][lane] = qv.z * SCALE;
    Qt[p * 4 + 3][lane] = qv.w * SCALE;
  }

  float acc_o[8][8];
#pragma unroll
  for (int i = 0; i < 8; ++i)
#pragma unroll
    for (int j = 0; j < 8; ++j) acc_o[i][j] = 0.0f;
  float mrow[8], lrow[8];
#pragma unroll
  for (int i = 0; i < 8; ++i) {
    mrow[i] = -1e30f;
    lrow[i] = 0.0f;
  }

  const int ntile = blockIdx.x * 2 + 2;  // (q0+64)/32
  for (int t = 0; t < ntile; ++t) {
    const int kb = t * 32;
    __syncthreads();  // prev tile fully consumed (also orders Qt staging)
    // stage K transposed: k = lane&31, two d4 per pass
#pragma unroll
    for (int p = 0; p < 8; ++p) {
      const int k = lane & 31;
      const int d4 = (p << 1) | (lane >> 5);
      float4 kv = *(const float4*)&K[base + (size_t)(kb + k) * 64 + d4 * 4];
      Kt[d4 * 4 + 0][k] = kv.x;
      Kt[d4 * 4 + 1][k] = kv.y;
      Kt[d4 * 4 + 2][k] = kv.z;
      Kt[d4 * 4 + 3][k] = kv.w;
    }
    // stage V direct copy [k][d]
#pragma unroll
    for (int p = 0; p < 8; ++p) {
      const int fi = p * 64 + lane;
      const int k = fi >> 4, d4 = fi & 15;
      *(float4*)&Vs[k][d4 * 4] =
          *(const float4*)&V[base + (size_t)(kb + k) * 64 + d4 * 4];
    }
    __syncthreads();

    // scores: 64q x 32k, micro 8(q) x 4(k) per lane; Q pre-scaled
    float acc_s[8][4];
#pragma unroll
    for (int i = 0; i < 8; ++i)
#pragma unroll
      for (int j = 0; j < 4; ++j) acc_s[i][j] = 0.0f;
#pragma unroll 4
    for (int d = 0; d < 64; ++d) {
      float4 qa0 = *(const float4*)&Qt[d][ly * 8];
      float4 qa1 = *(const float4*)&Qt[d][ly * 8 + 4];
      float4 kf = *(const float4*)&Kt[d][lx * 4];
      float qv[8] = {qa0.x, qa0.y, qa0.z, qa0.w, qa1.x, qa1.y, qa1.z, qa1.w};
      float kv[4] = {kf.x, kf.y, kf.z, kf.w};
#pragma unroll
      for (int i = 0; i < 8; ++i)
#pragma unroll
        for (int j = 0; j < 4; ++j)
          acc_s[i][j] = fmaf(qv[i], kv[j], acc_s[i][j]);
    }

    // online softmax per q row (8 lanes along lx hold 4 cols each)
#pragma unroll
    for (int i = 0; i < 8; ++i) {
      const int qg = q0 + ly * 8 + i;
      float rmax = -3.0e38f;
#pragma unroll
      for (int j = 0; j < 4; ++j) {
        const int kg = kb + lx * 4 + j;
        float sv = acc_s[i][j];
        if (kg > qg) sv = -3.0e38f;  // causal mask (matches ref through exp->0)
        acc_s[i][j] = sv;
        rmax = fmaxf(rmax, sv);
      }
      rmax = fmaxf(rmax, __shfl_xor(rmax, 1));
      rmax = fmaxf(rmax, __shfl_xor(rmax, 2));
      rmax = fmaxf(rmax, __shfl_xor(rmax, 4));
      const float mnew = fmaxf(mrow[i], rmax);
      const float alpha = __expf(mrow[i] - mnew);
      mrow[i] = mnew;
      float rsum = 0.0f;
#pragma unroll
      for (int j = 0; j < 4; ++j) {
        const float pv = __expf(acc_s[i][j] - mnew);
        acc_s[i][j] = pv;
        rsum += pv;
      }
      rsum += __shfl_xor(rsum, 1);
      rsum += __shfl_xor(rsum, 2);
      rsum += __shfl_xor(rsum, 4);
      lrow[i] = lrow[i] * alpha + rsum;
#pragma unroll
      for (int j = 0; j < 8; ++j) acc_o[i][j] *= alpha;
      // P write, swizzled: col (lx^ly)*4 .. +3  (8-way on write, reads clean)
      *(float4*)&Pm[ly * 8 + i][(lx ^ ly) * 4] =
          make_float4(acc_s[i][0], acc_s[i][1], acc_s[i][2], acc_s[i][3]);
    }
    __syncthreads();

    // PV: acc_o[i][j] += P[q][k] * V[k][d],  d = lx*8 + j
#pragma unroll 2
    for (int kc = 0; kc < 32; kc += 4) {
      float4 pv[8];
#pragma unroll
      for (int i = 0; i < 8; ++i)
        pv[i] = *(const float4*)&Pm[ly * 8 + i][kc ^ (ly * 4)];
      float pmat[4][8];
#pragma unroll
      for (int i = 0; i < 8; ++i) {
        pmat[0][i] = pv[i].x;
        pmat[1][i] = pv[i].y;
        pmat[2][i] = pv[i].z;
        pmat[3][i] = pv[i].w;
      }
#pragma unroll
      for (int kk = 0; kk < 4; ++kk) {
        float4 v0 = *(const float4*)&Vs[kc + kk][lx * 8];
        float4 v1 = *(const float4*)&Vs[kc + kk][lx * 8 + 4];
        float vv[8] = {v0.x, v0.y, v0.z, v0.w, v1.x, v1.y, v1.z, v1.w};
#pragma unroll
        for (int i = 0; i < 8; ++i)
#pragma unroll
          for (int j = 0; j < 8; ++j)
            acc_o[i][j] = fmaf(pmat[kk][i], vv[j], acc_o[i][j]);
      }
    }
  }

  // epilogue: divide by l, write flat [b*S+q][h*64+d]
  const int b = bh >> 4, h = bh & 15;
#pragma unroll
  for (int i = 0; i < 8; ++i) {
    const int qg = q0 + ly * 8 + i;
    const float inv = 1.0f / lrow[i];
    const size_t rb = (size_t)(b * S_LEN + qg) * 1024 + h * 64 + lx * 8;
    *(float4*)&O[rb] = make_float4(acc_o[i][0] * inv, acc_o[i][1] * inv,
                                   acc_o[i][2] * inv, acc_o[i][3] * inv);
    *(float4*)&O[rb + 4] = make_float4(acc_o[i][4] * inv, acc_o[i][5] * inv,
                                       acc_o[i][6] * inv, acc_o[i][7] * inv);
  }
}

// -------------------------------------------------------------- launch ----
extern "C" void kernel_launch(void* const* d_in, const int* in_sizes, int n_in,
                              void* d_out, int out_size, void* d_ws,
                              size_t ws_size, hipStream_t stream) {
  (void)in_sizes;
  (void)n_in;
  (void)out_size;
  (void)ws_size;
  const float* x = (const float*)d_in[0];
  const float* Wq = (const float*)d_in[1];
  const float* Wk = (const float*)d_in[2];
  const float* Wv = (const float*)d_in[3];
  const float* Wo = (const float*)d_in[4];
  float* out = (float*)d_out;

  float* ws = (float*)d_ws;
  const size_t MSZ = (size_t)4096 * 1024;
  float* qws = ws;
  float* kws = ws + MSZ;
  float* vws = ws + 2 * MSZ;
  float* aws = ws + 3 * MSZ;  // needs 64 MB of workspace total

  gemm_f32<0><<<dim3(32, 8, 3), 256, 0, stream>>>(x, Wq, Wk, Wv, qws, kws, vws);
  attn_f32<<<dim3(32, 32), 64, 0, stream>>>(qws, kws, vws, aws);
  gemm_f32<1><<<dim3(32, 8, 1), 256, 0, stream>>>(aws, Wo, Wo, Wo, out, out, out);
}

// Round 2
// 582.644 us; speedup vs baseline: 1.6524x; 1.6524x over previous
//
#include <hip/hip_runtime.h>

// MHA forward, round 2: bf16 MFMA GEMMs (m97 128^2 structure) + multi-wave
// fp32 flash attention. B=2, S=2048, D=1024, H=16, DH=64, scale=1/32.
//
// Pipeline:
//   0) cast_x:       x fp32 -> bf16 [4096][1024]
//   1) transpose_w:  Wq/Wk/Wv/Wo fp32 [K][N] -> bf16 Wt [N][K]
//   2) gemm_bf16<0>: xb @ Wt{q,k,v} (grid.z): z=0,1 -> Q,K bf16 [b,h,s,d];
//                    z=2 -> V fp32 [b,h,s,d]
//   3) attn_mw:      causal flash attn, 4 waves/block, q-tile 128, kv-tile 32;
//                    writes bf16 flat [4096][1024]
//   4) gemm_bf16<1>: attn @ Wt_o -> d_out fp32
//
// ws layout: xb 8MB @0 | Wt 4x2MB @8MB | Qb 8MB @16MB | Kb 8MB @24MB |
//            Vf 16MB @32MB | Ab 8MB @48MB   (total 56MB)

#define AS1 __attribute__((address_space(1)))
#define AS3 __attribute__((address_space(3)))

typedef __attribute__((ext_vector_type(4))) float f32x4;
typedef __attribute__((ext_vector_type(8))) short bf16x8;

__device__ __forceinline__ void gload16(const void* g, void* l) {
  __builtin_amdgcn_global_load_lds((const AS1 unsigned int*)g,
                                   (AS3 unsigned int*)l, 16, 0, 0);
}

__device__ __forceinline__ unsigned short f2b(float f) {  // RNE fp32->bf16
  unsigned u = __float_as_uint(f);
  return (unsigned short)((u + 0x7FFFu + ((u >> 16) & 1u)) >> 16);
}

// --------------------------------------------------------------- casts ----
__global__ __launch_bounds__(256) void cast_x_kernel(
    const float* __restrict__ x, unsigned short* __restrict__ xb) {
  const size_t i = (size_t)(blockIdx.x * 256 + threadIdx.x) * 4;
  float4 v = *(const float4*)&x[i];
  uint2 o;
  o.x = f2b(v.x) | ((unsigned)f2b(v.y) << 16);
  o.y = f2b(v.z) | ((unsigned)f2b(v.w) << 16);
  *(uint2*)&xb[i] = o;
}

// W fp32 [1024][1024] (K-major rows) -> Wt bf16 [N][K]
__global__ __launch_bounds__(256) void transpose_w(
    const float* __restrict__ W0, const float* __restrict__ W1,
    const float* __restrict__ W2, const float* __restrict__ W3,
    unsigned short* __restrict__ Wt) {
  __shared__ float T[64][65];
  const int tid = threadIdx.x;
  const int kb = blockIdx.x * 64, nb = blockIdx.y * 64, z = blockIdx.z;
  const float* W = (z == 0) ? W0 : (z == 1) ? W1 : (z == 2) ? W2 : W3;
  unsigned short* D = Wt + (size_t)z * 1024 * 1024;

#pragma unroll
  for (int p = 0; p < 4; ++p) {
    const int idx = p * 256 + tid;
    const int r = idx >> 4, c4 = idx & 15;
    float4 v = *(const float4*)&W[(size_t)(kb + r) * 1024 + nb + c4 * 4];
    T[r][c4 * 4 + 0] = v.x;
    T[r][c4 * 4 + 1] = v.y;
    T[r][c4 * 4 + 2] = v.z;
    T[r][c4 * 4 + 3] = v.w;
  }
  __syncthreads();
#pragma unroll
  for (int p = 0; p < 4; ++p) {
    const int idx = p * 256 + tid;
    const int n = idx >> 4, k4 = idx & 15;
    uint2 o;
    o.x = f2b(T[k4 * 4 + 0][n]) | ((unsigned)f2b(T[k4 * 4 + 1][n]) << 16);
    o.y = f2b(T[k4 * 4 + 2][n]) | ((unsigned)f2b(T[k4 * 4 + 3][n]) << 16);
    *(uint2*)&D[(size_t)(nb + n) * 1024 + kb + k4 * 4] = o;
  }
}

// ---------------------------------------------------------- bf16 GEMM ----
// C[4096x1024] = A[4096x1024] @ Bt^T, Bt stored [N][K] bf16.
// 128x128 tile, BK=32, 4 waves each 64x64, mfma_f32_16x16x32_bf16.
// KIND 0: QKV launch (z selects Bt/output; z<2 bf16 scatter, z=2 fp32 scatter)
// KIND 1: final, flat fp32 out.
template <int KIND>
__global__ __launch_bounds__(256) void gemm_bf16(
    const unsigned short* __restrict__ A, const unsigned short* __restrict__ B0,
    const unsigned short* __restrict__ B1, const unsigned short* __restrict__ B2,
    unsigned short* __restrict__ Oq, unsigned short* __restrict__ Ok,
    float* __restrict__ Ov) {
  __shared__ unsigned short As[128 * 32];
  __shared__ unsigned short Bs[128 * 32];
  const int tid = threadIdx.x, lane = tid & 63, w = tid >> 6;
  const int bm = blockIdx.x, bn = blockIdx.y, z = blockIdx.z;
  const unsigned short* __restrict__ Bt = (z == 0) ? B0 : (z == 1) ? B1 : B2;
  const int wr = w >> 1, wc = w & 1;

  f32x4 acc[4][4];
#pragma unroll
  for (int m = 0; m < 4; ++m)
#pragma unroll
    for (int n = 0; n < 4; ++n) acc[m][n] = (f32x4)0.0f;

  const int srow = lane >> 2;         // 0..15 within 16-row group
  const int scol = (lane & 3) * 8;    // k-chunk of 8 bf16 (16B)
  const int fr = lane & 15, fk = (lane >> 4) * 8;

  for (int kc = 0; kc < 1024; kc += 32) {
    __syncthreads();  // prev tile consumed
#pragma unroll
    for (int q = 0; q < 2; ++q) {
      const int r = w * 32 + q * 16;
      gload16(&A[(size_t)(bm * 128 + r + srow) * 1024 + kc + scol],
              &As[r * 32]);
      gload16(&Bt[(size_t)(bn * 128 + r + srow) * 1024 + kc + scol],
              &Bs[r * 32]);
    }
    __syncthreads();  // vmcnt(0) drained by compiler before barrier

    bf16x8 af[4], bf[4];
#pragma unroll
    for (int m = 0; m < 4; ++m)
      af[m] = *(const bf16x8*)&As[(wr * 64 + m * 16 + fr) * 32 + fk];
#pragma unroll
    for (int n = 0; n < 4; ++n)
      bf[n] = *(const bf16x8*)&Bs[(wc * 64 + n * 16 + fr) * 32 + fk];
#pragma unroll
    for (int m = 0; m < 4; ++m)
#pragma unroll
      for (int n = 0; n < 4; ++n)
        acc[m][n] =
            __builtin_amdgcn_mfma_f32_16x16x32_bf16(af[m], bf[n], acc[m][n], 0, 0, 0);
  }

  // epilogue: C/D layout col=lane&15, row=(lane>>4)*4+rr
  const int fq = lane >> 4;
#pragma unroll
  for (int mf = 0; mf < 4; ++mf) {
#pragma unroll
    for (int nf = 0; nf < 4; ++nf) {
      const int col = bn * 128 + wc * 64 + nf * 16 + fr;
#pragma unroll
      for (int rr = 0; rr < 4; ++rr) {
        const int m = bm * 128 + wr * 64 + mf * 16 + fq * 4 + rr;
        const float val = acc[mf][nf][rr];
        if constexpr (KIND == 0) {
          const int b = m >> 11, s = m & 2047;
          const int h = col >> 6, d = col & 63;
          const size_t o = ((size_t)(b * 16 + h) * 2048 + s) * 64 + d;
          if (z == 2)
            Ov[o] = val;
          else if (z == 1)
            Ok[o] = f2b(val);
          else
            Oq[o] = f2b(val);
        } else {
          Ov[(size_t)m * 1024 + col] = val;
        }
      }
    }
  }
}

// ----------------------------------------------------------- attention ----
// 4 waves/block, q-tile 128 (32 rows/wave), kv-tile 32. fp32 compute.
// Q,K bf16 [b,h,s,64]; V fp32 [b,h,s,64]; out bf16 flat [4096][1024].
__global__ __launch_bounds__(256) void attn_mw(
    const unsigned short* __restrict__ Qb, const unsigned short* __restrict__ Kb,
    const float* __restrict__ Vf, unsigned short* __restrict__ Ab) {
  __shared__ float Qt[64][128];  // [d][q], pre-scaled
  __shared__ float Kt[64][32];   // [d][k]
  __shared__ float Vs[32][64];   // [k][d]
  __shared__ float Pm[128][32];  // per-wave 32-row slabs, col-xor swizzled

  const int tid = threadIdx.x, lane = tid & 63, w = tid >> 6;
  const int lx = lane & 7, ly = lane >> 3;
  const int bq = blockIdx.x, bh = blockIdx.y;
  const int q0 = bq * 128, wq0 = w * 32;
  const size_t base = (size_t)bh * 2048 * 64;

  // stage Q transposed + scaled (one-time; write conflicts acceptable)
#pragma unroll
  for (int p = 0; p < 4; ++p) {
    const int idx = p * 256 + tid;
    const int q = idx >> 3, d8 = idx & 7;
    uint4 raw = *(const uint4*)&Qb[base + (size_t)(q0 + q) * 64 + d8 * 8];
    const unsigned rw[4] = {raw.x, raw.y, raw.z, raw.w};
#pragma unroll
    for (int j = 0; j < 4; ++j) {
      Qt[d8 * 8 + j * 2 + 0][q] = __uint_as_float(rw[j] << 16) * 0.03125f;
      Qt[d8 * 8 + j * 2 + 1][q] = __uint_as_float(rw[j] & 0xffff0000u) * 0.03125f;
    }
  }

  float acc_o[4][8];
#pragma unroll
  for (int i = 0; i < 4; ++i)
#pragma unroll
    for (int j = 0; j < 8; ++j) acc_o[i][j] = 0.0f;
  float mrow[4], lrow[4];
#pragma unroll
  for (int i = 0; i < 4; ++i) {
    mrow[i] = -1e30f;
    lrow[i] = 0.0f;
  }

  const int ntile = bq * 4 + 4;
  const int wlast = bq * 4 + w;  // last tile this wave computes

  for (int t = 0; t < ntile; ++t) {
    const int kb = t * 32;
    __syncthreads();  // prev tile fully consumed (orders Qt staging at t=0)
    {  // K stage: conflict-free transposed write (lanes span k)
      const int k = tid & 31, d8 = tid >> 5;
      uint4 raw = *(const uint4*)&Kb[base + (size_t)(kb + k) * 64 + d8 * 8];
      const unsigned rw[4] = {raw.x, raw.y, raw.z, raw.w};
#pragma unroll
      for (int j = 0; j < 4; ++j) {
        Kt[d8 * 8 + j * 2 + 0][k] = __uint_as_float(rw[j] << 16);
        Kt[d8 * 8 + j * 2 + 1][k] = __uint_as_float(rw[j] & 0xffff0000u);
      }
    }
#pragma unroll
    for (int p = 0; p < 2; ++p) {  // V stage, coalesced float4
      const int idx = p * 256 + tid;
      const int k = idx >> 4, d4 = idx & 15;
      *(float4*)&Vs[k][d4 * 4] =
          *(const float4*)&Vf[base + (size_t)(kb + k) * 64 + d4 * 4];
    }
    __syncthreads();

    if (t <= wlast) {
      // scores: 32q x 32k per wave, 4x4 micro per lane
      float acc_s[4][4];
#pragma unroll
      for (int i = 0; i < 4; ++i)
#pragma unroll
        for (int j = 0; j < 4; ++j) acc_s[i][j] = 0.0f;
#pragma unroll 8
      for (int d = 0; d < 64; ++d) {
        float4 qv = *(const float4*)&Qt[d][wq0 + ly * 4];
        float4 kv = *(const float4*)&Kt[d][lx * 4];
        const float qa[4] = {qv.x, qv.y, qv.z, qv.w};
        const float ka[4] = {kv.x, kv.y, kv.z, kv.w};
#pragma unroll
        for (int i = 0; i < 4; ++i)
#pragma unroll
          for (int j = 0; j < 4; ++j)
            acc_s[i][j] = fmaf(qa[i], ka[j], acc_s[i][j]);
      }
      // online softmax (8 lanes along lx per row)
#pragma unroll
      for (int i = 0; i < 4; ++i) {
        const int qg = q0 + wq0 + ly * 4 + i;
        float rmax = -3.0e38f;
#pragma unroll
        for (int j = 0; j < 4; ++j) {
          const int kg = kb + lx * 4 + j;
          float sv = acc_s[i][j];
          if (kg > qg) sv = -3.0e38f;  // causal
          acc_s[i][j] = sv;
          rmax = fmaxf(rmax, sv);
        }
        rmax = fmaxf(rmax, __shfl_xor(rmax, 1));
        rmax = fmaxf(rmax, __shfl_xor(rmax, 2));
        rmax = fmaxf(rmax, __shfl_xor(rmax, 4));
        const float mnew = fmaxf(mrow[i], rmax);
        const float alpha = __expf(mrow[i] - mnew);
        mrow[i] = mnew;
        float rsum = 0.0f;
#pragma unroll
        for (int j = 0; j < 4; ++j) {
          const float pv = __expf(acc_s[i][j] - mnew);
          acc_s[i][j] = pv;
          rsum += pv;
        }
        rsum += __shfl_xor(rsum, 1);
        rsum += __shfl_xor(rsum, 2);
        rsum += __shfl_xor(rsum, 4);
        lrow[i] = lrow[i] * alpha + rsum;
#pragma unroll
        for (int j = 0; j < 8; ++j) acc_o[i][j] *= alpha;
        *(float4*)&Pm[wq0 + ly * 4 + i][(lx ^ ly) * 4] =
            make_float4(acc_s[i][0], acc_s[i][1], acc_s[i][2], acc_s[i][3]);
      }
      // PV (Pm slab is wave-private; lgkmcnt orders write->read)
#pragma unroll 2
      for (int kc = 0; kc < 32; kc += 4) {
        float4 pv[4];
#pragma unroll
        for (int i = 0; i < 4; ++i)
          pv[i] = *(const float4*)&Pm[wq0 + ly * 4 + i][((kc >> 2) ^ ly) * 4];
        float pmat[4][4];
#pragma unroll
        for (int i = 0; i < 4; ++i) {
          pmat[0][i] = pv[i].x;
          pmat[1][i] = pv[i].y;
          pmat[2][i] = pv[i].z;
          pmat[3][i] = pv[i].w;
        }
#pragma unroll
        for (int kk = 0; kk < 4; ++kk) {
          float4 v0 = *(const float4*)&Vs[kc + kk][lx * 8];
          float4 v1 = *(const float4*)&Vs[kc + kk][lx * 8 + 4];
          const float vv[8] = {v0.x, v0.y, v0.z, v0.w, v1.x, v1.y, v1.z, v1.w};
#pragma unroll
          for (int i = 0; i < 4; ++i)
#pragma unroll
            for (int j = 0; j < 8; ++j)
              acc_o[i][j] = fmaf(pmat[kk][i], vv[j], acc_o[i][j]);
        }
      }
    }
  }

  // epilogue -> bf16 flat [b*2048+q][h*64+d]
  const int b = bh >> 4, h = bh & 15;
#pragma unroll
  for (int i = 0; i < 4; ++i) {
    const int qg = q0 + wq0 + ly * 4 + i;
    const float inv = 1.0f / lrow[i];
    uint4 o;
    o.x = f2b(acc_o[i][0] * inv) | ((unsigned)f2b(acc_o[i][1] * inv) << 16);
    o.y = f2b(acc_o[i][2] * inv) | ((unsigned)f2b(acc_o[i][3] * inv) << 16);
    o.z = f2b(acc_o[i][4] * inv) | ((unsigned)f2b(acc_o[i][5] * inv) << 16);
    o.w = f2b(acc_o[i][6] * inv) | ((unsigned)f2b(acc_o[i][7] * inv) << 16);
    *(uint4*)&Ab[(size_t)(b * 2048 + qg) * 1024 + h * 64 + lx * 8] = o;
  }
}

// -------------------------------------------------------------- launch ----
extern "C" void kernel_launch(void* const* d_in, const int* in_sizes, int n_in,
                              void* d_out, int out_size, void* d_ws,
                              size_t ws_size, hipStream_t stream) {
  (void)in_sizes; (void)n_in; (void)out_size; (void)ws_size;
  const float* x = (const float*)d_in[0];
  const float* Wq = (const float*)d_in[1];
  const float* Wk = (const float*)d_in[2];
  const float* Wv = (const float*)d_in[3];
  const float* Wo = (const float*)d_in[4];
  float* out = (float*)d_out;

  char* ws = (char*)d_ws;
  unsigned short* xb = (unsigned short*)(ws);                    // 8MB
  unsigned short* Wt = (unsigned short*)(ws + (8u << 20));       // 4x2MB
  unsigned short* Qb = (unsigned short*)(ws + (16u << 20));      // 8MB
  unsigned short* Kb = (unsigned short*)(ws + (24u << 20));      // 8MB
  float* Vf = (float*)(ws + (32u << 20));                        // 16MB
  unsigned short* Ab = (unsigned short*)(ws + (48u << 20));      // 8MB
  unsigned short* Wtq = Wt;
  unsigned short* Wtk = Wt + (1u << 20);
  unsigned short* Wtv = Wt + (2u << 20);
  unsigned short* Wto = Wt + (3u << 20);

  cast_x_kernel<<<dim3(4096), 256, 0, stream>>>(x, xb);
  transpose_w<<<dim3(16, 16, 4), 256, 0, stream>>>(Wq, Wk, Wv, Wo, Wt);
  gemm_bf16<0><<<dim3(32, 8, 3), 256, 0, stream>>>(xb, Wtq, Wtk, Wtv, Qb, Kb, Vf);
  attn_mw<<<dim3(16, 32), 256, 0, stream>>>(Qb, Kb, Vf, Ab);
  gemm_bf16<1><<<dim3(32, 8, 1), 256, 0, stream>>>(Ab, Wto, Wto, Wto, nullptr,
                                                   nullptr, out);
}

// Round 3
// 200.202 us; speedup vs baseline: 4.8090x; 2.9103x over previous
//
#include <hip/hip_runtime.h>

// MHA forward, round 3: MFMA everywhere.
// B=2, S=2048, D=1024, H=16, DH=64, scale=1/32 (folded into exp args).
//
// Pipeline:
//   0) cast_x:       x fp32 -> bf16 [4096][1024]
//   1) transpose_w:  W* fp32 [K][N] -> bf16 Wt [N][K]
//   2) gemm_bf16<0>: xb @ Wt{q,k,v}; z=0,1 -> Q,K bf16 [b,h,s,d];
//                    z=2 -> V bf16 TRANSPOSED [b,h,d,s]
//   3) attn_mfma:    causal flash attn, 4 waves, q-tile 128, kv-tile 64,
//                    bf16 MFMA QK^T + PV, dbuf LDS; out bf16 [4096][1024]
//   4) gemm_bf16<1>: @ Wt_o -> d_out fp32
//
// ws: xb 8MB@0 | Wt 8MB@8 | Qb 8MB@16 | Kb 8MB@24 | Vt 8MB@32 | Ab 8MB@40.

#define AS1 __attribute__((address_space(1)))
#define AS3 __attribute__((address_space(3)))
#define SCALE 0.03125f

typedef __attribute__((ext_vector_type(4))) float f32x4;
typedef __attribute__((ext_vector_type(8))) short bf16x8;

__device__ __forceinline__ void gload16(const void* g, void* l) {
  __builtin_amdgcn_global_load_lds((const AS1 unsigned int*)g,
                                   (AS3 unsigned int*)l, 16, 0, 0);
}

__device__ __forceinline__ unsigned short f2b(float f) {  // RNE fp32->bf16
  unsigned u = __float_as_uint(f);
  return (unsigned short)((u + 0x7FFFu + ((u >> 16) & 1u)) >> 16);
}

// --------------------------------------------------------------- casts ----
__global__ __launch_bounds__(256) void cast_x_kernel(
    const float* __restrict__ x, unsigned short* __restrict__ xb) {
  const size_t i = (size_t)(blockIdx.x * 256 + threadIdx.x) * 4;
  float4 v = *(const float4*)&x[i];
  uint2 o;
  o.x = f2b(v.x) | ((unsigned)f2b(v.y) << 16);
  o.y = f2b(v.z) | ((unsigned)f2b(v.w) << 16);
  *(uint2*)&xb[i] = o;
}

__global__ __launch_bounds__(256) void transpose_w(
    const float* __restrict__ W0, const float* __restrict__ W1,
    const float* __restrict__ W2, const float* __restrict__ W3,
    unsigned short* __restrict__ Wt) {
  __shared__ float T[64][65];
  const int tid = threadIdx.x;
  const int kb = blockIdx.x * 64, nb = blockIdx.y * 64, z = blockIdx.z;
  const float* W = (z == 0) ? W0 : (z == 1) ? W1 : (z == 2) ? W2 : W3;
  unsigned short* D = Wt + (size_t)z * 1024 * 1024;
#pragma unroll
  for (int p = 0; p < 4; ++p) {
    const int idx = p * 256 + tid;
    const int r = idx >> 4, c4 = idx & 15;
    float4 v = *(const float4*)&W[(size_t)(kb + r) * 1024 + nb + c4 * 4];
    T[r][c4 * 4 + 0] = v.x;
    T[r][c4 * 4 + 1] = v.y;
    T[r][c4 * 4 + 2] = v.z;
    T[r][c4 * 4 + 3] = v.w;
  }
  __syncthreads();
#pragma unroll
  for (int p = 0; p < 4; ++p) {
    const int idx = p * 256 + tid;
    const int n = idx >> 4, k4 = idx & 15;
    uint2 o;
    o.x = f2b(T[k4 * 4 + 0][n]) | ((unsigned)f2b(T[k4 * 4 + 1][n]) << 16);
    o.y = f2b(T[k4 * 4 + 2][n]) | ((unsigned)f2b(T[k4 * 4 + 3][n]) << 16);
    *(uint2*)&D[(size_t)(nb + n) * 1024 + kb + k4 * 4] = o;
  }
}

// ---------------------------------------------------------- bf16 GEMM ----
// C[4096x1024] = A @ Bt^T (Bt [N][K] bf16). 128x128 tile, BK=32, 4 waves.
// KIND 0: z=0 -> Oq bf16 [b,h,s,d]; z=1 -> Ok same; z=2 -> Ovt bf16 [b,h,d,s]
// KIND 1: Of fp32 flat [4096][1024]
template <int KIND>
__global__ __launch_bounds__(256) void gemm_bf16(
    const unsigned short* __restrict__ A, const unsigned short* __restrict__ B0,
    const unsigned short* __restrict__ B1, const unsigned short* __restrict__ B2,
    unsigned short* __restrict__ Oq, unsigned short* __restrict__ Ok,
    unsigned short* __restrict__ Ovt, float* __restrict__ Of) {
  __shared__ unsigned short As[128 * 32];
  __shared__ unsigned short Bs[128 * 32];
  const int tid = threadIdx.x, lane = tid & 63, w = tid >> 6;
  const int bm = blockIdx.x, bn = blockIdx.y, z = blockIdx.z;
  const unsigned short* __restrict__ Bt = (z == 0) ? B0 : (z == 1) ? B1 : B2;
  const int wr = w >> 1, wc = w & 1;

  f32x4 acc[4][4];
#pragma unroll
  for (int m = 0; m < 4; ++m)
#pragma unroll
    for (int n = 0; n < 4; ++n) acc[m][n] = (f32x4)0.0f;

  const int srow = lane >> 2;
  const int scol = (lane & 3) * 8;
  const int fr = lane & 15, fk = (lane >> 4) * 8;

  for (int kc = 0; kc < 1024; kc += 32) {
    __syncthreads();
#pragma unroll
    for (int q = 0; q < 2; ++q) {
      const int r = w * 32 + q * 16;
      gload16(&A[(size_t)(bm * 128 + r + srow) * 1024 + kc + scol], &As[r * 32]);
      gload16(&Bt[(size_t)(bn * 128 + r + srow) * 1024 + kc + scol], &Bs[r * 32]);
    }
    __syncthreads();

    bf16x8 af[4], bf[4];
#pragma unroll
    for (int m = 0; m < 4; ++m)
      af[m] = *(const bf16x8*)&As[(wr * 64 + m * 16 + fr) * 32 + fk];
#pragma unroll
    for (int n = 0; n < 4; ++n)
      bf[n] = *(const bf16x8*)&Bs[(wc * 64 + n * 16 + fr) * 32 + fk];
#pragma unroll
    for (int m = 0; m < 4; ++m)
#pragma unroll
      for (int n = 0; n < 4; ++n)
        acc[m][n] = __builtin_amdgcn_mfma_f32_16x16x32_bf16(af[m], bf[n],
                                                            acc[m][n], 0, 0, 0);
  }

  const int fq = lane >> 4;
#pragma unroll
  for (int mf = 0; mf < 4; ++mf) {
#pragma unroll
    for (int nf = 0; nf < 4; ++nf) {
      const int col = bn * 128 + wc * 64 + nf * 16 + fr;
#pragma unroll
      for (int rr = 0; rr < 4; ++rr) {
        const int m = bm * 128 + wr * 64 + mf * 16 + fq * 4 + rr;
        const float val = acc[mf][nf][rr];
        if constexpr (KIND == 0) {
          const int b = m >> 11, s = m & 2047;
          const int h = col >> 6, d = col & 63;
          if (z == 2)  // V transposed: [b,h,d,s]
            Ovt[((size_t)(b * 16 + h) * 64 + d) * 2048 + s] = f2b(val);
          else if (z == 1)
            Ok[((size_t)(b * 16 + h) * 2048 + s) * 64 + d] = f2b(val);
          else
            Oq[((size_t)(b * 16 + h) * 2048 + s) * 64 + d] = f2b(val);
        } else {
          Of[(size_t)m * 1024 + col] = val;
        }
      }
    }
  }
}

// ----------------------------------------------------------- attention ----
// 4 waves/block; wave owns 32 q-rows (2 m-frags); kv-tile 64; dbuf LDS.
// Q,K bf16 [b,h,s,64]; V bf16 [b,h,64,s]; out bf16 flat [4096][1024].
__global__ __launch_bounds__(256) void attn_mfma(
    const unsigned short* __restrict__ Qb, const unsigned short* __restrict__ Kb,
    const unsigned short* __restrict__ Vt, unsigned short* __restrict__ Ab) {
  __shared__ unsigned short Ks[2][64 * 64];  // [buf][k-row * 64 + d], chunk-XOR
  __shared__ unsigned short Vs[2][64 * 64];  // [buf][d-row * 64 + k], chunk-XOR
  __shared__ unsigned short Pl[4][32][72];   // per-wave P, +16B row pad

  const int tid = threadIdx.x, lane = tid & 63, w = tid >> 6;
  const int lo = lane & 15, hi = lane >> 4;

  // balance remap: CU pairs (bq, 15-bq) -> constant 34 kv-tiles per CU
  const int id = blockIdx.x;
  const int rhalf = id >> 8, j = id & 255;
  const int bh = j & 31;
  const int bq = rhalf ? (15 - (j >> 5)) : (j >> 5);

  const int q0 = bq * 128;
  const int qw = q0 + w * 32;
  const size_t base = (size_t)bh * (2048 * 64);

  // Q fragments live in registers for the whole kernel (raw; scale in exp)
  bf16x8 qf[2][2];  // [mf][ks]
#pragma unroll
  for (int mf = 0; mf < 2; ++mf)
#pragma unroll
    for (int ks = 0; ks < 2; ++ks)
      qf[mf][ks] = *(const bf16x8*)&Qb[base + (size_t)(qw + mf * 16 + lo) * 64 +
                                       ks * 32 + hi * 8];

  f32x4 acc[2][4];
#pragma unroll
  for (int mf = 0; mf < 2; ++mf)
#pragma unroll
    for (int nf = 0; nf < 4; ++nf) acc[mf][nf] = (f32x4)0.0f;
  float mrow[2][4], lrow[2][4];
#pragma unroll
  for (int mf = 0; mf < 2; ++mf)
#pragma unroll
    for (int rr = 0; rr < 4; ++rr) {
      mrow[mf][rr] = -1e30f;
      lrow[mf][rr] = 0.0f;
    }

  const int ntile = 2 * bq + 2;
  const int wlast = 2 * bq + (w >> 1);

  // stage tile kb into buf: K rows contiguous (stride 64), Vt rows stride 2048
  const unsigned short* kgb = Kb + base;
  const unsigned short* vgb = Vt + base;
  const int lseg = (w * 64) * 8;  // wave's ushort offset within 256-slot pass

#define STAGE(BUF, KBASE)                                                    \
  {                                                                          \
    const int kb_ = (KBASE);                                                 \
    _Pragma("unroll") for (int qq = 0; qq < 2; ++qq) {                       \
      const int slot = qq * 256 + tid;                                       \
      const int row = slot >> 3, ch = (slot & 7) ^ (row & 7);                \
      const int lb = qq * 4096 / 2 * 2; /* qq*256 slots *8 ushorts */        \
      gload16(kgb + (size_t)(kb_ + row) * 64 + ch * 8,                       \
              &Ks[BUF][qq * 2048 + lseg]);                                   \
      gload16(vgb + (size_t)row * 2048 + kb_ + ch * 8,                       \
              &Vs[BUF][qq * 2048 + lseg]);                                   \
      (void)lb;                                                              \
    }                                                                        \
  }

  STAGE(0, 0)
  int cur = 0;

  for (int t = 0; t < ntile; ++t) {
    __syncthreads();  // buf[cur] staged (vmcnt(0) drained per-wave by compiler)
    if (t + 1 < ntile) STAGE(cur ^ 1, (t + 1) * 64)

    if (t <= wlast) {
      const int kb = t * 64;
      // ---- QK^T ----
      bf16x8 kf[2][4];
#pragma unroll
      for (int nf = 0; nf < 4; ++nf) {
        const int row = nf * 16 + lo;
#pragma unroll
        for (int ks = 0; ks < 2; ++ks) {
          const int ch = (ks * 4 + hi) ^ (row & 7);
          kf[ks][nf] = *(const bf16x8*)&Ks[cur][row * 64 + ch * 8];
        }
      }
      f32x4 s[2][4];
#pragma unroll
      for (int mf = 0; mf < 2; ++mf)
#pragma unroll
        for (int nf = 0; nf < 4; ++nf) s[mf][nf] = (f32x4)0.0f;
#pragma unroll
      for (int ks = 0; ks < 2; ++ks)
#pragma unroll
        for (int mf = 0; mf < 2; ++mf)
#pragma unroll
          for (int nf = 0; nf < 4; ++nf)
            s[mf][nf] = __builtin_amdgcn_mfma_f32_16x16x32_bf16(
                qf[mf][ks], kf[ks][nf], s[mf][nf], 0, 0, 0);

      // ---- online softmax (S layout: col=k=nf*16+lo, row=q=mf*16+hi*4+rr)
      const bool domask = (kb + 63 > qw);
#pragma unroll
      for (int mf = 0; mf < 2; ++mf) {
#pragma unroll
        for (int rr = 0; rr < 4; ++rr) {
          const int qg = qw + mf * 16 + hi * 4 + rr;
          float v[4];
#pragma unroll
          for (int nf = 0; nf < 4; ++nf) {
            v[nf] = s[mf][nf][rr];
            if (domask && (kb + nf * 16 + lo > qg)) v[nf] = -1e30f;
          }
          float mx = fmaxf(fmaxf(v[0], v[1]), fmaxf(v[2], v[3]));
          mx = fmaxf(mx, __shfl_xor(mx, 1));
          mx = fmaxf(mx, __shfl_xor(mx, 2));
          mx = fmaxf(mx, __shfl_xor(mx, 4));
          mx = fmaxf(mx, __shfl_xor(mx, 8));
          const float mold = mrow[mf][rr];
          const float mnew = fmaxf(mold, mx);
          const float al = __expf((mold - mnew) * SCALE);
          float p[4], rs = 0.0f;
#pragma unroll
          for (int nf = 0; nf < 4; ++nf) {
            p[nf] = __expf((v[nf] - mnew) * SCALE);
            rs += p[nf];
          }
          rs += __shfl_xor(rs, 1);
          rs += __shfl_xor(rs, 2);
          rs += __shfl_xor(rs, 4);
          rs += __shfl_xor(rs, 8);
          lrow[mf][rr] = lrow[mf][rr] * al + rs;
          mrow[mf][rr] = mnew;
#pragma unroll
          for (int nf = 0; nf < 4; ++nf) acc[mf][nf][rr] *= al;
          const int qloc = mf * 16 + hi * 4 + rr;
#pragma unroll
          for (int nf = 0; nf < 4; ++nf)
            Pl[w][qloc][nf * 16 + lo] = f2b(p[nf]);
        }
      }

      // ---- PV ---- (P wave-private; compiler orders ds_write->ds_read)
      bf16x8 pa[2][2], vf[2][4];
#pragma unroll
      for (int mf = 0; mf < 2; ++mf)
#pragma unroll
        for (int ks = 0; ks < 2; ++ks)
          pa[mf][ks] = *(const bf16x8*)&Pl[w][mf * 16 + lo][(ks * 4 + hi) * 8];
#pragma unroll
      for (int nf = 0; nf < 4; ++nf) {
        const int row = nf * 16 + lo;
#pragma unroll
        for (int ks = 0; ks < 2; ++ks) {
          const int ch = (ks * 4 + hi) ^ (row & 7);
          vf[ks][nf] = *(const bf16x8*)&Vs[cur][row * 64 + ch * 8];
        }
      }
#pragma unroll
      for (int ks = 0; ks < 2; ++ks)
#pragma unroll
        for (int mf = 0; mf < 2; ++mf)
#pragma unroll
          for (int nf = 0; nf < 4; ++nf)
            acc[mf][nf] = __builtin_amdgcn_mfma_f32_16x16x32_bf16(
                pa[mf][ks], vf[ks][nf], acc[mf][nf], 0, 0, 0);
    }
    cur ^= 1;
  }

  // epilogue: normalize, write bf16 flat [b*2048+q][h*64+d]
  const int b = bh >> 4, h = bh & 15;
#pragma unroll
  for (int mf = 0; mf < 2; ++mf)
#pragma unroll
    for (int rr = 0; rr < 4; ++rr) {
      const int qg = qw + mf * 16 + hi * 4 + rr;
      const float inv = 1.0f / lrow[mf][rr];
      const size_t ob = (size_t)(b * 2048 + qg) * 1024 + h * 64;
#pragma unroll
      for (int nf = 0; nf < 4; ++nf)
        Ab[ob + nf * 16 + lo] = f2b(acc[mf][nf][rr] * inv);
    }
}

// -------------------------------------------------------------- launch ----
extern "C" void kernel_launch(void* const* d_in, const int* in_sizes, int n_in,
                              void* d_out, int out_size, void* d_ws,
                              size_t ws_size, hipStream_t stream) {
  (void)in_sizes; (void)n_in; (void)out_size; (void)ws_size;
  const float* x = (const float*)d_in[0];
  const float* Wq = (const float*)d_in[1];
  const float* Wk = (const float*)d_in[2];
  const float* Wv = (const float*)d_in[3];
  const float* Wo = (const float*)d_in[4];
  float* out = (float*)d_out;

  char* ws = (char*)d_ws;
  unsigned short* xb = (unsigned short*)(ws);                // 8MB
  unsigned short* Wt = (unsigned short*)(ws + (8u << 20));   // 4x2MB
  unsigned short* Qb = (unsigned short*)(ws + (16u << 20));  // 8MB
  unsigned short* Kb = (unsigned short*)(ws + (24u << 20));  // 8MB
  unsigned short* Vt = (unsigned short*)(ws + (32u << 20));  // 8MB
  unsigned short* Ab = (unsigned short*)(ws + (40u << 20));  // 8MB
  unsigned short* Wtq = Wt;
  unsigned short* Wtk = Wt + (1u << 20);
  unsigned short* Wtv = Wt + (2u << 20);
  unsigned short* Wto = Wt + (3u << 20);

  cast_x_kernel<<<dim3(4096), 256, 0, stream>>>(x, xb);
  transpose_w<<<dim3(16, 16, 4), 256, 0, stream>>>(Wq, Wk, Wv, Wo, Wt);
  gemm_bf16<0><<<dim3(32, 8, 3), 256, 0, stream>>>(xb, Wtq, Wtk, Wtv, Qb, Kb,
                                                   Vt, nullptr);
  attn_mfma<<<dim3(512), 256, 0, stream>>>(Qb, Kb, Vt, Ab);
  gemm_bf16<1><<<dim3(32, 8, 1), 256, 0, stream>>>(Ab, Wto, Wto, Wto, nullptr,
                                                   nullptr, nullptr, out);
}

// Round 4
// 129.096 us; speedup vs baseline: 7.4577x; 1.5508x over previous
//
#include <hip/hip_runtime.h>

// MHA forward, round 4: swapped-operand attention (S^T = K·Q^T), P stays in
// registers via k-axis permutation sigma; V pre-permuted by vperm kernel.
// B=2, S=2048, D=1024, H=16, DH=64, scale=1/32 folded into exp2 constant.
//
// Pipeline:
//   0) cast_x, transpose_w
//   1) gemm_bf16<0>: xb @ Wt{q,k,v} -> Qb/Kb/Vb bf16 [b,h,s,64] (all coalesced)
//   2) vperm: Vb -> Vp bf16 [b,h,64,2048], columns sigma-permuted per 64-tile
//   3) attn_swp: causal flash attn, swapped MFMA, out bf16 [4096][1024]
//   4) gemm_bf16<1>: @ Wt_o -> d_out fp32
//
// ws: xb 8@0 | Wt 8@8 | Qb 8@16 | Kb 8@24 | Vb 8@32 | Vp 8@40 | Ab 8@48 (56MB)

#define AS1 __attribute__((address_space(1)))
#define AS3 __attribute__((address_space(3)))
#define EXPC2 0.04508422f  // (1/32) * log2(e)

typedef __attribute__((ext_vector_type(4))) float f32x4;
typedef __attribute__((ext_vector_type(8))) short bf16x8;

__device__ __forceinline__ void gload16(const void* g, void* l) {
  __builtin_amdgcn_global_load_lds((const AS1 unsigned int*)g,
                                   (AS3 unsigned int*)l, 16, 0, 0);
}
__device__ __forceinline__ unsigned short f2b(float f) {  // RNE fp32->bf16
  unsigned u = __float_as_uint(f);
  return (unsigned short)((u + 0x7FFFu + ((u >> 16) & 1u)) >> 16);
}
__device__ __forceinline__ float fexp2(float x) {
  float r;
  asm("v_exp_f32 %0, %1" : "=v"(r) : "v"(x));
  return r;
}
__device__ __forceinline__ unsigned cvtpk(float a, float b) {  // [a|b] bf16x2
  unsigned r;
  asm("v_cvt_pk_bf16_f32 %0, %1, %2" : "=v"(r) : "v"(a), "v"(b));
  return r;
}

// --------------------------------------------------------------- casts ----
__global__ __launch_bounds__(256) void cast_x_kernel(
    const float* __restrict__ x, unsigned short* __restrict__ xb) {
  const size_t i = (size_t)(blockIdx.x * 256 + threadIdx.x) * 4;
  float4 v = *(const float4*)&x[i];
  uint2 o;
  o.x = f2b(v.x) | ((unsigned)f2b(v.y) << 16);
  o.y = f2b(v.z) | ((unsigned)f2b(v.w) << 16);
  *(uint2*)&xb[i] = o;
}

__global__ __launch_bounds__(256) void transpose_w(
    const float* __restrict__ W0, const float* __restrict__ W1,
    const float* __restrict__ W2, const float* __restrict__ W3,
    unsigned short* __restrict__ Wt) {
  __shared__ float T[64][65];
  const int tid = threadIdx.x;
  const int kb = blockIdx.x * 64, nb = blockIdx.y * 64, z = blockIdx.z;
  const float* W = (z == 0) ? W0 : (z == 1) ? W1 : (z == 2) ? W2 : W3;
  unsigned short* D = Wt + (size_t)z * 1024 * 1024;
#pragma unroll
  for (int p = 0; p < 4; ++p) {
    const int idx = p * 256 + tid;
    const int r = idx >> 4, c4 = idx & 15;
    float4 v = *(const float4*)&W[(size_t)(kb + r) * 1024 + nb + c4 * 4];
    T[r][c4 * 4 + 0] = v.x;
    T[r][c4 * 4 + 1] = v.y;
    T[r][c4 * 4 + 2] = v.z;
    T[r][c4 * 4 + 3] = v.w;
  }
  __syncthreads();
#pragma unroll
  for (int p = 0; p < 4; ++p) {
    const int idx = p * 256 + tid;
    const int n = idx >> 4, k4 = idx & 15;
    uint2 o;
    o.x = f2b(T[k4 * 4 + 0][n]) | ((unsigned)f2b(T[k4 * 4 + 1][n]) << 16);
    o.y = f2b(T[k4 * 4 + 2][n]) | ((unsigned)f2b(T[k4 * 4 + 3][n]) << 16);
    *(uint2*)&D[(size_t)(nb + n) * 1024 + kb + k4 * 4] = o;
  }
}

// ---------------------------------------------------------- bf16 GEMM ----
// C[4096x1024] = A @ Bt^T (Bt [N][K] bf16). 128x128 tile, BK=32, 4 waves.
// KIND 0: z selects Bt and bf16 output [b,h,s,d] (coalesced). KIND 1: fp32 flat.
template <int KIND>
__global__ __launch_bounds__(256) void gemm_bf16(
    const unsigned short* __restrict__ A, const unsigned short* __restrict__ B0,
    const unsigned short* __restrict__ B1, const unsigned short* __restrict__ B2,
    unsigned short* __restrict__ O0, unsigned short* __restrict__ O1,
    unsigned short* __restrict__ O2, float* __restrict__ Of) {
  __shared__ unsigned short As[128 * 32];
  __shared__ unsigned short Bs[128 * 32];
  const int tid = threadIdx.x, lane = tid & 63, w = tid >> 6;
  const int bm = blockIdx.x, bn = blockIdx.y, z = blockIdx.z;
  const unsigned short* __restrict__ Bt = (z == 0) ? B0 : (z == 1) ? B1 : B2;
  unsigned short* __restrict__ Ob = (z == 0) ? O0 : (z == 1) ? O1 : O2;
  const int wr = w >> 1, wc = w & 1;

  f32x4 acc[4][4];
#pragma unroll
  for (int m = 0; m < 4; ++m)
#pragma unroll
    for (int n = 0; n < 4; ++n) acc[m][n] = (f32x4)0.0f;

  const int srow = lane >> 2, scol = (lane & 3) * 8;
  const int fr = lane & 15, fk = (lane >> 4) * 8;

  for (int kc = 0; kc < 1024; kc += 32) {
    __syncthreads();
#pragma unroll
    for (int q = 0; q < 2; ++q) {
      const int r = w * 32 + q * 16;
      gload16(&A[(size_t)(bm * 128 + r + srow) * 1024 + kc + scol], &As[r * 32]);
      gload16(&Bt[(size_t)(bn * 128 + r + srow) * 1024 + kc + scol], &Bs[r * 32]);
    }
    __syncthreads();

    bf16x8 af[4], bf[4];
#pragma unroll
    for (int m = 0; m < 4; ++m)
      af[m] = *(const bf16x8*)&As[(wr * 64 + m * 16 + fr) * 32 + fk];
#pragma unroll
    for (int n = 0; n < 4; ++n)
      bf[n] = *(const bf16x8*)&Bs[(wc * 64 + n * 16 + fr) * 32 + fk];
#pragma unroll
    for (int m = 0; m < 4; ++m)
#pragma unroll
      for (int n = 0; n < 4; ++n)
        acc[m][n] = __builtin_amdgcn_mfma_f32_16x16x32_bf16(af[m], bf[n],
                                                            acc[m][n], 0, 0, 0);
  }

  const int fq = lane >> 4;
#pragma unroll
  for (int mf = 0; mf < 4; ++mf) {
#pragma unroll
    for (int nf = 0; nf < 4; ++nf) {
      const int col = bn * 128 + wc * 64 + nf * 16 + fr;
#pragma unroll
      for (int rr = 0; rr < 4; ++rr) {
        const int m = bm * 128 + wr * 64 + mf * 16 + fq * 4 + rr;
        const float val = acc[mf][nf][rr];
        if constexpr (KIND == 0) {
          const int b = m >> 11, s = m & 2047;
          const int h = col >> 6, d = col & 63;
          Ob[((size_t)(b * 16 + h) * 2048 + s) * 64 + d] = f2b(val);
        } else {
          Of[(size_t)m * 1024 + col] = val;
        }
      }
    }
  }
}

// ------------------------------------------------------------- vperm -----
// Vb [b,h,s,64] -> Vp [b,h,64,2048] with sigma column permutation per 64-tile:
// Vp[bh][d][t*64+c] = Vb[bh][t*64+sigma(c)][d],
// sigma(c) = (ks*2 + (j>>2))*16 + hi*4 + (j&3), c = ks*32 + hi*8 + j.
__global__ __launch_bounds__(256) void vperm(
    const unsigned short* __restrict__ Vb, unsigned short* __restrict__ Vp) {
  __shared__ unsigned short T[64][72];
  const int tid = threadIdx.x;
  const int t = blockIdx.x, bh = blockIdx.y;
  const size_t ibase = (size_t)bh * 2048 * 64 + (size_t)t * 64 * 64;
#pragma unroll
  for (int p = 0; p < 2; ++p) {
    const int slot = p * 256 + tid;
    const int r = slot >> 3, c8 = slot & 7;
    *(uint4*)&T[r][c8 * 8] = *(const uint4*)&Vb[ibase + r * 64 + c8 * 8];
  }
  __syncthreads();
  const int d = tid >> 2, cg = (tid & 3) * 16;
  unsigned short tmp[16];
#pragma unroll
  for (int i = 0; i < 16; ++i) {
    const int c = cg + i;
    const int ks = c >> 5, hi = (c >> 3) & 3, j = c & 7;
    const int s = (ks * 2 + (j >> 2)) * 16 + hi * 4 + (j & 3);
    tmp[i] = T[s][d];
  }
  unsigned short* o = &Vp[(size_t)bh * 64 * 2048 + (size_t)d * 2048 + t * 64 + cg];
  *(uint4*)o = *(uint4*)&tmp[0];
  *(uint4*)(o + 8) = *(uint4*)&tmp[8];
}

// ----------------------------------------------------------- attention ----
// 4 waves; wave owns 32 q (2 n-frags, q=lo); kv-tile 64; dbuf LDS staging.
// Swapped: S^T = mfma(K, Q^T); P in-register -> PV B-operand; O^T via mfma,
// transposed back through wave-private LDS slab in epilogue.
__global__ __launch_bounds__(256) void attn_swp(
    const unsigned short* __restrict__ Qb, const unsigned short* __restrict__ Kb,
    const unsigned short* __restrict__ Vp, unsigned short* __restrict__ Ab) {
  __shared__ unsigned short Ks[2][64 * 64];  // [buf][k*64 + d] chunk-XOR
  __shared__ unsigned short Vv[2][64 * 64];  // [buf][d*64 + c] chunk-XOR
  __shared__ unsigned short Ot[4][32][72];   // per-wave O transpose slab

  const int tid = threadIdx.x, lane = tid & 63, w = tid >> 6;
  const int lo = lane & 15, hi = lane >> 4;

  // balance remap: CU gets (bq, 15-bq) pair -> constant work
  const int id = blockIdx.x;
  const int rhalf = id >> 8, j0 = id & 255;
  const int bh = j0 & 31;
  const int bq = rhalf ? (15 - (j0 >> 5)) : (j0 >> 5);

  const int qw = bq * 128 + w * 32;
  const size_t base = (size_t)bh * (2048 * 64);

  // Q as B-operand fragments: B[d][q], col q = lo, rows d = ks*32 + hi*8 + j
  bf16x8 qfB[2][2];  // [qn][ks]
#pragma unroll
  for (int qn = 0; qn < 2; ++qn)
#pragma unroll
    for (int ks = 0; ks < 2; ++ks)
      qfB[qn][ks] = *(const bf16x8*)&Qb[base + (size_t)(qw + qn * 16 + lo) * 64 +
                                        ks * 32 + hi * 8];

  f32x4 accO[4][2];  // [mf(d)][qn], col q = lo, row d = mf*16+hi*4+rr
#pragma unroll
  for (int mf = 0; mf < 4; ++mf)
#pragma unroll
    for (int qn = 0; qn < 2; ++qn) accO[mf][qn] = (f32x4)0.0f;
  float mrow[2] = {-1e30f, -1e30f};  // running max (raw score) per q-col
  float lpart[2] = {0.0f, 0.0f};     // per-lane partial denominator

  const int ntile = 2 * bq + 2;
  const int wlast = 2 * bq + (w >> 1);

  const unsigned short* kgb = Kb + base;
  const unsigned short* vgb = Vp + base;
  const int lseg = w * 512;  // wave's ushort offset per 256-slot pass

#define STAGE(BUF, KBASE)                                                  \
  {                                                                        \
    const int kb_ = (KBASE);                                               \
    _Pragma("unroll") for (int qq = 0; qq < 2; ++qq) {                     \
      const int slot = qq * 256 + tid;                                     \
      const int row = slot >> 3, ch = (slot & 7) ^ (row & 7);              \
      gload16(kgb + (size_t)(kb_ + row) * 64 + ch * 8,                     \
              &Ks[BUF][qq * 2048 + lseg]);                                 \
      gload16(vgb + (size_t)row * 2048 + kb_ + ch * 8,                     \
              &Vv[BUF][qq * 2048 + lseg]);                                 \
    }                                                                      \
  }

  STAGE(0, 0)
  int cur = 0;

  for (int t = 0; t < ntile; ++t) {
    __syncthreads();  // buf[cur] resident (compiler drains vmcnt before barrier)
    if (t + 1 < ntile) STAGE(cur ^ 1, (t + 1) * 64)

    if (t <= wlast) {
      const int kb = t * 64;
      // K as A-operand: A[k][d], row k = kf*16+lo, cols d = ks*32+hi*8+j
      bf16x8 ka[2][4];
#pragma unroll
      for (int kf = 0; kf < 4; ++kf) {
        const int row = kf * 16 + lo;
#pragma unroll
        for (int ks = 0; ks < 2; ++ks) {
          const int ch = (ks * 4 + hi) ^ (row & 7);
          ka[ks][kf] = *(const bf16x8*)&Ks[cur][row * 64 + ch * 8];
        }
      }
      f32x4 st[4][2];  // S^T frags: col q = lo, row k = kf*16+hi*4+rr
#pragma unroll
      for (int kf = 0; kf < 4; ++kf)
#pragma unroll
        for (int qn = 0; qn < 2; ++qn) st[kf][qn] = (f32x4)0.0f;
      __builtin_amdgcn_s_setprio(1);
#pragma unroll
      for (int ks = 0; ks < 2; ++ks)
#pragma unroll
        for (int kf = 0; kf < 4; ++kf)
#pragma unroll
          for (int qn = 0; qn < 2; ++qn)
            st[kf][qn] = __builtin_amdgcn_mfma_f32_16x16x32_bf16(
                ka[ks][kf], qfB[qn][ks], st[kf][qn], 0, 0, 0);
      __builtin_amdgcn_s_setprio(0);

      // V as A-operand (issue early; lgkm hides under softmax)
      bf16x8 va[2][4];
#pragma unroll
      for (int mf = 0; mf < 4; ++mf) {
        const int row = mf * 16 + lo;
#pragma unroll
        for (int ks = 0; ks < 2; ++ks) {
          const int ch = (ks * 4 + hi) ^ (row & 7);
          va[ks][mf] = *(const bf16x8*)&Vv[cur][row * 64 + ch * 8];
        }
      }

      // softmax per q-col; lane holds k = kf*16 + hi*4 + rr (16 values)
      const bool domask = (kb + 63 > qw);
      bf16x8 pb[2][2];  // P^T B-operand frags [qn][ks]
#pragma unroll
      for (int qn = 0; qn < 2; ++qn) {
        float v[16];
#pragma unroll
        for (int kf = 0; kf < 4; ++kf)
#pragma unroll
          for (int rr = 0; rr < 4; ++rr) v[kf * 4 + rr] = st[kf][qn][rr];
        if (domask) {
          const int qg = qw + qn * 16 + lo;
#pragma unroll
          for (int kf = 0; kf < 4; ++kf)
#pragma unroll
            for (int rr = 0; rr < 4; ++rr)
              if (kb + kf * 16 + hi * 4 + rr > qg) v[kf * 4 + rr] = -1e30f;
        }
        float mx01 = fmaxf(v[0], v[1]), mx23 = fmaxf(v[2], v[3]);
        float mx45 = fmaxf(v[4], v[5]), mx67 = fmaxf(v[6], v[7]);
        float mx89 = fmaxf(v[8], v[9]), mxab = fmaxf(v[10], v[11]);
        float mxcd = fmaxf(v[12], v[13]), mxef = fmaxf(v[14], v[15]);
        float mx = fmaxf(fmaxf(fmaxf(mx01, mx23), fmaxf(mx45, mx67)),
                         fmaxf(fmaxf(mx89, mxab), fmaxf(mxcd, mxef)));
        mx = fmaxf(mx, __shfl_xor(mx, 16));
        mx = fmaxf(mx, __shfl_xor(mx, 32));
        const float mold = mrow[qn];
        const float mnew = fmaxf(mold, mx);
        const float al = fexp2((mold - mnew) * EXPC2);
        mrow[qn] = mnew;
        float p[16], rs = 0.0f;
#pragma unroll
        for (int i = 0; i < 16; ++i) {
          p[i] = fexp2((v[i] - mnew) * EXPC2);
          rs += p[i];
        }
        lpart[qn] = lpart[qn] * al + rs;
#pragma unroll
        for (int mf = 0; mf < 4; ++mf)
#pragma unroll
          for (int rr = 0; rr < 4; ++rr) accO[mf][qn][rr] *= al;
        // pack: pb[qn][ks] reg j holds p[ks*8+j]  (= P^T at position c)
#pragma unroll
        for (int ks = 0; ks < 2; ++ks) {
          uint4 u;
          u.x = cvtpk(p[ks * 8 + 0], p[ks * 8 + 1]);
          u.y = cvtpk(p[ks * 8 + 2], p[ks * 8 + 3]);
          u.z = cvtpk(p[ks * 8 + 4], p[ks * 8 + 5]);
          u.w = cvtpk(p[ks * 8 + 6], p[ks * 8 + 7]);
          pb[qn][ks] = *(bf16x8*)&u;
        }
      }

      __builtin_amdgcn_s_setprio(1);
#pragma unroll
      for (int ks = 0; ks < 2; ++ks)
#pragma unroll
        for (int mf = 0; mf < 4; ++mf)
#pragma unroll
          for (int qn = 0; qn < 2; ++qn)
            accO[mf][qn] = __builtin_amdgcn_mfma_f32_16x16x32_bf16(
                va[ks][mf], pb[qn][ks], accO[mf][qn], 0, 0, 0);
      __builtin_amdgcn_s_setprio(0);
    }
    cur ^= 1;
  }

  // epilogue: reduce l across hi-lanes, normalize, transpose via LDS, store
  float linv[2];
#pragma unroll
  for (int qn = 0; qn < 2; ++qn) {
    float l = lpart[qn];
    l += __shfl_xor(l, 16);
    l += __shfl_xor(l, 32);
    linv[qn] = 1.0f / l;
  }
#pragma unroll
  for (int mf = 0; mf < 4; ++mf)
#pragma unroll
    for (int qn = 0; qn < 2; ++qn) {
      uint2 u;
      u.x = cvtpk(accO[mf][qn][0] * linv[qn], accO[mf][qn][1] * linv[qn]);
      u.y = cvtpk(accO[mf][qn][2] * linv[qn], accO[mf][qn][3] * linv[qn]);
      *(uint2*)&Ot[w][qn * 16 + lo][mf * 16 + hi * 4] = u;
    }
  // wave-private slab: compiler inserts lgkm wait; no barrier needed
  const int b = bh >> 4, h = bh & 15;
  const int row = lane & 31, half = lane >> 5;
  uint4 o0 = *(const uint4*)&Ot[w][row][half * 32];
  uint4 o1 = *(const uint4*)&Ot[w][row][half * 32 + 8];
  uint4 o2 = *(const uint4*)&Ot[w][row][half * 32 + 16];
  uint4 o3 = *(const uint4*)&Ot[w][row][half * 32 + 24];
  unsigned short* op =
      &Ab[(size_t)(b * 2048 + qw + row) * 1024 + h * 64 + half * 32];
  *(uint4*)(op + 0) = o0;
  *(uint4*)(op + 8) = o1;
  *(uint4*)(op + 16) = o2;
  *(uint4*)(op + 24) = o3;
}

// -------------------------------------------------------------- launch ----
extern "C" void kernel_launch(void* const* d_in, const int* in_sizes, int n_in,
                              void* d_out, int out_size, void* d_ws,
                              size_t ws_size, hipStream_t stream) {
  (void)in_sizes; (void)n_in; (void)out_size; (void)ws_size;
  const float* x = (const float*)d_in[0];
  const float* Wq = (const float*)d_in[1];
  const float* Wk = (const float*)d_in[2];
  const float* Wv = (const float*)d_in[3];
  const float* Wo = (const float*)d_in[4];
  float* out = (float*)d_out;

  char* ws = (char*)d_ws;
  unsigned short* xb = (unsigned short*)(ws);                // 8MB
  unsigned short* Wt = (unsigned short*)(ws + (8u << 20));   // 4x2MB
  unsigned short* Qb = (unsigned short*)(ws + (16u << 20));  // 8MB
  unsigned short* Kb = (unsigned short*)(ws + (24u << 20));  // 8MB
  unsigned short* Vb = (unsigned short*)(ws + (32u << 20));  // 8MB
  unsigned short* Vp = (unsigned short*)(ws + (40u << 20));  // 8MB
  unsigned short* Ab = (unsigned short*)(ws + (48u << 20));  // 8MB
  unsigned short* Wtq = Wt;
  unsigned short* Wtk = Wt + (1u << 20);
  unsigned short* Wtv = Wt + (2u << 20);
  unsigned short* Wto = Wt + (3u << 20);

  cast_x_kernel<<<dim3(4096), 256, 0, stream>>>(x, xb);
  transpose_w<<<dim3(16, 16, 4), 256, 0, stream>>>(Wq, Wk, Wv, Wo, Wt);
  gemm_bf16<0><<<dim3(32, 8, 3), 256, 0, stream>>>(xb, Wtq, Wtk, Wtv, Qb, Kb,
                                                   Vb, nullptr);
  vperm<<<dim3(32, 32), 256, 0, stream>>>(Vb, Vp);
  attn_swp<<<dim3(512), 256, 0, stream>>>(Qb, Kb, Vp, Ab);
  gemm_bf16<1><<<dim3(32, 8, 1), 256, 0, stream>>>(Ab, Wto, Wto, Wto, nullptr,
                                                   nullptr, nullptr, out);
}

// Round 5
// 120.659 us; speedup vs baseline: 7.9792x; 1.0699x over previous
//
#include <hip/hip_runtime.h>

// MHA forward, round 5.
// B=2, S=2048, D=1024, H=16, DH=64, scale=1/32 folded into exp2 constant.
//
// Pipeline (5 kernels):
//   0) cast_x, transpose_w
//   1) gemm_bf16<0>: xb @ Wt{q,k} -> Qb/Kb bf16 [b,h,s,64]
//   2) gemm_bf16<2>: Wtv @ xb^T   -> Vp bf16 [b,h,64,2048], sigma-permuted
//   3) attn_q64:     causal flash attn, q-tile 64, 4 waves, out bf16 [4096][1024]
//   4) gemm_bf16<1>: @ Wt_o -> d_out fp32
//
// ws: xb 8@0 | Wt 8@8 | Qb 8@16 | Kb 8@24 | Vp 8@32 | Ab 8@40  (48MB)

#define AS1 __attribute__((address_space(1)))
#define AS3 __attribute__((address_space(3)))
#define EXPC2 0.04508422f  // (1/32) * log2(e)

typedef __attribute__((ext_vector_type(4))) float f32x4;
typedef __attribute__((ext_vector_type(8))) short bf16x8;

__device__ __forceinline__ void gload16(const void* g, void* l) {
  __builtin_amdgcn_global_load_lds((const AS1 unsigned int*)g,
                                   (AS3 unsigned int*)l, 16, 0, 0);
}
__device__ __forceinline__ unsigned short f2b(float f) {  // RNE fp32->bf16
  unsigned u = __float_as_uint(f);
  return (unsigned short)((u + 0x7FFFu + ((u >> 16) & 1u)) >> 16);
}
__device__ __forceinline__ float fexp2(float x) {
  float r;
  asm("v_exp_f32 %0, %1" : "=v"(r) : "v"(x));
  return r;
}
__device__ __forceinline__ unsigned cvtpk(float a, float b) {  // [a|b] bf16x2
  unsigned r;
  asm("v_cvt_pk_bf16_f32 %0, %1, %2" : "=v"(r) : "v"(a), "v"(b));
  return r;
}

// --------------------------------------------------------------- casts ----
__global__ __launch_bounds__(256) void cast_x_kernel(
    const float* __restrict__ x, unsigned short* __restrict__ xb) {
  const size_t i = (size_t)(blockIdx.x * 256 + threadIdx.x) * 4;
  float4 v = *(const float4*)&x[i];
  uint2 o;
  o.x = f2b(v.x) | ((unsigned)f2b(v.y) << 16);
  o.y = f2b(v.z) | ((unsigned)f2b(v.w) << 16);
  *(uint2*)&xb[i] = o;
}

__global__ __launch_bounds__(256) void transpose_w(
    const float* __restrict__ W0, const float* __restrict__ W1,
    const float* __restrict__ W2, const float* __restrict__ W3,
    unsigned short* __restrict__ Wt) {
  __shared__ float T[64][65];
  const int tid = threadIdx.x;
  const int kb = blockIdx.x * 64, nb = blockIdx.y * 64, z = blockIdx.z;
  const float* W = (z == 0) ? W0 : (z == 1) ? W1 : (z == 2) ? W2 : W3;
  unsigned short* D = Wt + (size_t)z * 1024 * 1024;
#pragma unroll
  for (int p = 0; p < 4; ++p) {
    const int idx = p * 256 + tid;
    const int r = idx >> 4, c4 = idx & 15;
    float4 v = *(const float4*)&W[(size_t)(kb + r) * 1024 + nb + c4 * 4];
    T[r][c4 * 4 + 0] = v.x;
    T[r][c4 * 4 + 1] = v.y;
    T[r][c4 * 4 + 2] = v.z;
    T[r][c4 * 4 + 3] = v.w;
  }
  __syncthreads();
#pragma unroll
  for (int p = 0; p < 4; ++p) {
    const int idx = p * 256 + tid;
    const int n = idx >> 4, k4 = idx & 15;
    uint2 o;
    o.x = f2b(T[k4 * 4 + 0][n]) | ((unsigned)f2b(T[k4 * 4 + 1][n]) << 16);
    o.y = f2b(T[k4 * 4 + 2][n]) | ((unsigned)f2b(T[k4 * 4 + 3][n]) << 16);
    *(uint2*)&D[(size_t)(nb + n) * 1024 + kb + k4 * 4] = o;
  }
}

// ---------------------------------------------------------- bf16 GEMM ----
// C[M x N] = A @ Bt^T (A [M][K] K-major, Bt [N][K] K-major, bf16).
// 128x128 tile, BK=32, 4 waves. Epilogues:
// KIND 0: z in {0,1} selects Bt/output; bf16 [b,h,s,d] scatter (coalesced)
// KIND 1: fp32 flat [4096][1024]
// KIND 2: V^T: m = h*64+d, col = s; write Vp[b,h,d][t*64 + sigma^-1(u)] bf16
template <int KIND>
__global__ __launch_bounds__(256) void gemm_bf16(
    const unsigned short* __restrict__ A, const unsigned short* __restrict__ B0,
    const unsigned short* __restrict__ B1, unsigned short* __restrict__ O0,
    unsigned short* __restrict__ O1, float* __restrict__ Of) {
  __shared__ unsigned short As[128 * 32];
  __shared__ unsigned short Bs[128 * 32];
  const int tid = threadIdx.x, lane = tid & 63, w = tid >> 6;
  const int bm = blockIdx.x, bn = blockIdx.y, z = blockIdx.z;
  const unsigned short* __restrict__ Bt = (z == 0) ? B0 : B1;
  unsigned short* __restrict__ Ob = (z == 0) ? O0 : O1;
  const int wr = w >> 1, wc = w & 1;

  f32x4 acc[4][4];
#pragma unroll
  for (int m = 0; m < 4; ++m)
#pragma unroll
    for (int n = 0; n < 4; ++n) acc[m][n] = (f32x4)0.0f;

  const int srow = lane >> 2, scol = (lane & 3) * 8;
  const int fr = lane & 15, fk = (lane >> 4) * 8;

  for (int kc = 0; kc < 1024; kc += 32) {
    __syncthreads();
#pragma unroll
    for (int q = 0; q < 2; ++q) {
      const int r = w * 32 + q * 16;
      gload16(&A[(size_t)(bm * 128 + r + srow) * 1024 + kc + scol], &As[r * 32]);
      gload16(&Bt[(size_t)(bn * 128 + r + srow) * 1024 + kc + scol], &Bs[r * 32]);
    }
    __syncthreads();

    bf16x8 af[4], bf[4];
#pragma unroll
    for (int m = 0; m < 4; ++m)
      af[m] = *(const bf16x8*)&As[(wr * 64 + m * 16 + fr) * 32 + fk];
#pragma unroll
    for (int n = 0; n < 4; ++n)
      bf[n] = *(const bf16x8*)&Bs[(wc * 64 + n * 16 + fr) * 32 + fk];
#pragma unroll
    for (int m = 0; m < 4; ++m)
#pragma unroll
      for (int n = 0; n < 4; ++n)
        acc[m][n] = __builtin_amdgcn_mfma_f32_16x16x32_bf16(af[m], bf[n],
                                                            acc[m][n], 0, 0, 0);
  }

  const int fq = lane >> 4;
#pragma unroll
  for (int mf = 0; mf < 4; ++mf) {
#pragma unroll
    for (int nf = 0; nf < 4; ++nf) {
      const int col = bn * 128 + wc * 64 + nf * 16 + fr;
#pragma unroll
      for (int rr = 0; rr < 4; ++rr) {
        const int m = bm * 128 + wr * 64 + mf * 16 + fq * 4 + rr;
        const float val = acc[mf][nf][rr];
        if constexpr (KIND == 0) {
          const int b = m >> 11, s = m & 2047;
          const int h = col >> 6, d = col & 63;
          Ob[((size_t)(b * 16 + h) * 2048 + s) * 64 + d] = f2b(val);
        } else if constexpr (KIND == 1) {
          Of[(size_t)m * 1024 + col] = val;
        } else {
          // V^T with sigma^-1 column placement within each 64-tile
          const int b = col >> 11, sl = col & 2047;
          const int t = sl >> 6, u = sl & 63;
          const int a = u >> 4;
          const int c =
              (a >> 1) * 32 + ((u >> 2) & 3) * 8 + (a & 1) * 4 + (u & 3);
          const int h = m >> 6, d = m & 63;
          O0[((size_t)(b * 16 + h) * 64 + d) * 2048 + t * 64 + c] = f2b(val);
        }
      }
    }
  }
}

// ----------------------------------------------------------- attention ----
// q-tile 64 (wave owns 16 q-rows), kv-tile 64, dbuf LDS, grid 1024 (LPT).
// Swapped MFMA: S^T = K·Q^T, P in-register (sigma-matched V), O^T accum.
// Q,K bf16 [b,h,s,64]; Vp bf16 [b,h,64,2048] sigma-permuted; out bf16 flat.
__global__ __launch_bounds__(256) void attn_q64(
    const unsigned short* __restrict__ Qb, const unsigned short* __restrict__ Kb,
    const unsigned short* __restrict__ Vp, unsigned short* __restrict__ Ab) {
  // 32KB: Ks dbuf @0/@4096, Vv dbuf @8192/@12288 (ushort idx); Ot aliases @0.
  __shared__ unsigned short smem[16384];

  const int tid = threadIdx.x, lane = tid & 63, w = tid >> 6;
  const int lo = lane & 15, hi = lane >> 4;

  const int id = blockIdx.x;
  const int bq = 31 - (id >> 5);  // LPT: longest kv-prefix first
  const int bh = id & 31;
  const int qw = bq * 64 + w * 16;
  const size_t base = (size_t)bh * (2048 * 64);

  // Q as B-operand: col q = lo, rows d = ks*32 + hi*8 + j (raw; scale in exp)
  bf16x8 qf[2];
#pragma unroll
  for (int ks = 0; ks < 2; ++ks)
    qf[ks] =
        *(const bf16x8*)&Qb[base + (size_t)(qw + lo) * 64 + ks * 32 + hi * 8];

  f32x4 accO[4];  // O^T: row d = mf*16+hi*4+rr, col q = lo
#pragma unroll
  for (int mf = 0; mf < 4; ++mf) accO[mf] = (f32x4)0.0f;
  float mrow = -1e30f, lpart = 0.0f;

  const int ntile = bq + 1;
  const unsigned short* kgb = Kb + base;
  const unsigned short* vgb = Vp + base;
  const int lseg = w * 512;

#define STAGE(BUF, KBASE)                                                    \
  {                                                                          \
    const int kb_ = (KBASE);                                                 \
    _Pragma("unroll") for (int qq = 0; qq < 2; ++qq) {                       \
      const int slot = qq * 256 + tid;                                       \
      const int row = slot >> 3, ch = (slot & 7) ^ (row & 7);                \
      gload16(kgb + (size_t)(kb_ + row) * 64 + ch * 8,                       \
              &smem[(BUF)*4096 + qq * 2048 + lseg]);                         \
      gload16(vgb + (size_t)row * 2048 + kb_ + ch * 8,                       \
              &smem[8192 + (BUF)*4096 + qq * 2048 + lseg]);                  \
    }                                                                        \
  }

  STAGE(0, 0)
  int cur = 0;

  for (int t = 0; t < ntile; ++t) {
    __syncthreads();  // buf[cur] resident (compiler drains vmcnt at barrier)
    if (t + 1 < ntile) STAGE(cur ^ 1, (t + 1) * 64)

    const int kb = t * 64;
    const int x7 = lo & 7;
    // K as A-operand: row k = kf*16+lo, cols d = ks*32+hi*8+j
    bf16x8 ka[2][4];
#pragma unroll
    for (int ks = 0; ks < 2; ++ks) {
      const int ch = (ks * 4 + hi) ^ x7;
#pragma unroll
      for (int kf = 0; kf < 4; ++kf)
        ka[ks][kf] =
            *(const bf16x8*)&smem[cur * 4096 + (kf * 16 + lo) * 64 + ch * 8];
    }
    f32x4 st[4];  // S^T: row k = kf*16+hi*4+rr, col q = lo
#pragma unroll
    for (int kf = 0; kf < 4; ++kf) st[kf] = (f32x4)0.0f;
    __builtin_amdgcn_s_setprio(1);
#pragma unroll
    for (int ks = 0; ks < 2; ++ks)
#pragma unroll
      for (int kf = 0; kf < 4; ++kf)
        st[kf] = __builtin_amdgcn_mfma_f32_16x16x32_bf16(ka[ks][kf], qf[ks],
                                                         st[kf], 0, 0, 0);
    __builtin_amdgcn_s_setprio(0);

    // V^T as A-operand (issue early; lgkm hides under softmax)
    bf16x8 va[2][4];
#pragma unroll
    for (int ks = 0; ks < 2; ++ks) {
      const int ch = (ks * 4 + hi) ^ x7;
#pragma unroll
      for (int mf = 0; mf < 4; ++mf)
        va[ks][mf] = *(const bf16x8*)&smem[8192 + cur * 4096 +
                                           (mf * 16 + lo) * 64 + ch * 8];
    }

    // ---- softmax: lane holds k = kf*16 + hi*4 + rr for q = qw + lo ----
    float v[16];
#pragma unroll
    for (int kf = 0; kf < 4; ++kf)
#pragma unroll
      for (int rr = 0; rr < 4; ++rr) v[kf * 4 + rr] = st[kf][rr];
    if (kb + 63 > qw) {  // only the diagonal tile
      const int qg = qw + lo;
#pragma unroll
      for (int kf = 0; kf < 4; ++kf)
#pragma unroll
        for (int rr = 0; rr < 4; ++rr)
          if (kb + kf * 16 + hi * 4 + rr > qg) v[kf * 4 + rr] = -1e30f;
    }
    float mx = fmaxf(fmaxf(fmaxf(v[0], v[1]), fmaxf(v[2], v[3])),
                     fmaxf(fmaxf(v[4], v[5]), fmaxf(v[6], v[7])));
    mx = fmaxf(mx, fmaxf(fmaxf(fmaxf(v[8], v[9]), fmaxf(v[10], v[11])),
                         fmaxf(fmaxf(v[12], v[13]), fmaxf(v[14], v[15]))));
    mx = fmaxf(mx, __shfl_xor(mx, 16));
    mx = fmaxf(mx, __shfl_xor(mx, 32));
    // T13 defer-rescale: skip unless max grew by > 64 raw units (p <= 2^2.9)
    if (!__all(mx - mrow <= 64.0f)) {
      const float mnew = fmaxf(mrow, mx);
      const float al = fexp2((mrow - mnew) * EXPC2);
      mrow = mnew;
      lpart *= al;
#pragma unroll
      for (int mf = 0; mf < 4; ++mf)
#pragma unroll
        for (int rr = 0; rr < 4; ++rr) accO[mf][rr] *= al;
    }
    float p[16], rs = 0.0f;
#pragma unroll
    for (int i = 0; i < 16; ++i) {
      p[i] = fexp2((v[i] - mrow) * EXPC2);
      rs += p[i];
    }
    lpart += rs;

    // pack P^T B-operand: reg j of frag ks = p[ks*8+j] (sigma-matched V)
    bf16x8 pb[2];
#pragma unroll
    for (int ks = 0; ks < 2; ++ks) {
      uint4 u;
      u.x = cvtpk(p[ks * 8 + 0], p[ks * 8 + 1]);
      u.y = cvtpk(p[ks * 8 + 2], p[ks * 8 + 3]);
      u.z = cvtpk(p[ks * 8 + 4], p[ks * 8 + 5]);
      u.w = cvtpk(p[ks * 8 + 6], p[ks * 8 + 7]);
      pb[ks] = *(bf16x8*)&u;
    }

    __builtin_amdgcn_s_setprio(1);
#pragma unroll
    for (int ks = 0; ks < 2; ++ks)
#pragma unroll
      for (int mf = 0; mf < 4; ++mf)
        accO[mf] = __builtin_amdgcn_mfma_f32_16x16x32_bf16(va[ks][mf], pb[ks],
                                                           accO[mf], 0, 0, 0);
    __builtin_amdgcn_s_setprio(0);
    cur ^= 1;
  }

  __syncthreads();  // staging LDS dead everywhere -> safe to alias Ot

  // epilogue: denominator, normalize, transpose via wave-private slab
  float l = lpart;
  l += __shfl_xor(l, 16);
  l += __shfl_xor(l, 32);
  const float linv = 1.0f / l;
  unsigned short* ot = &smem[w * 1152];  // [16 q][72 d-pad]
#pragma unroll
  for (int mf = 0; mf < 4; ++mf) {
    uint2 u;
    u.x = cvtpk(accO[mf][0] * linv, accO[mf][1] * linv);
    u.y = cvtpk(accO[mf][2] * linv, accO[mf][3] * linv);
    *(uint2*)&ot[lo * 72 + mf * 16 + hi * 4] = u;
  }
  // wave-private slab: compiler orders ds_write -> ds_read via lgkmcnt
  const int b = bh >> 4, h = bh & 15;
  const int row = lane >> 2, cg = (lane & 3) * 16;
  uint4 o0 = *(const uint4*)&ot[row * 72 + cg];
  uint4 o1 = *(const uint4*)&ot[row * 72 + cg + 8];
  unsigned short* op =
      &Ab[(size_t)(b * 2048 + qw + row) * 1024 + h * 64 + cg];
  *(uint4*)op = o0;
  *(uint4*)(op + 8) = o1;
}

// -------------------------------------------------------------- launch ----
extern "C" void kernel_launch(void* const* d_in, const int* in_sizes, int n_in,
                              void* d_out, int out_size, void* d_ws,
                              size_t ws_size, hipStream_t stream) {
  (void)in_sizes; (void)n_in; (void)out_size; (void)ws_size;
  const float* x = (const float*)d_in[0];
  const float* Wq = (const float*)d_in[1];
  const float* Wk = (const float*)d_in[2];
  const float* Wv = (const float*)d_in[3];
  const float* Wo = (const float*)d_in[4];
  float* out = (float*)d_out;

  char* ws = (char*)d_ws;
  unsigned short* xb = (unsigned short*)(ws);                // 8MB
  unsigned short* Wt = (unsigned short*)(ws + (8u << 20));   // 4x2MB
  unsigned short* Qb = (unsigned short*)(ws + (16u << 20));  // 8MB
  unsigned short* Kb = (unsigned short*)(ws + (24u << 20));  // 8MB
  unsigned short* Vp = (unsigned short*)(ws + (32u << 20));  // 8MB
  unsigned short* Ab = (unsigned short*)(ws + (40u << 20));  // 8MB
  unsigned short* Wtq = Wt;
  unsigned short* Wtk = Wt + (1u << 20);
  unsigned short* Wtv = Wt + (2u << 20);
  unsigned short* Wto = Wt + (3u << 20);

  cast_x_kernel<<<dim3(4096), 256, 0, stream>>>(x, xb);
  transpose_w<<<dim3(16, 16, 4), 256, 0, stream>>>(Wq, Wk, Wv, Wo, Wt);
  gemm_bf16<0><<<dim3(32, 8, 2), 256, 0, stream>>>(xb, Wtq, Wtk, Qb, Kb,
                                                   nullptr);
  gemm_bf16<2><<<dim3(8, 32, 1), 256, 0, stream>>>(Wtv, xb, nullptr, Vp,
                                                   nullptr, nullptr);
  attn_q64<<<dim3(1024), 256, 0, stream>>>(Qb, Kb, Vp, Ab);
  gemm_bf16<1><<<dim3(32, 8, 1), 256, 0, stream>>>(Ab, Wto, nullptr, nullptr,
                                                   nullptr, out);
}

// Round 6
// 118.657 us; speedup vs baseline: 8.1138x; 1.0169x over previous
//
#include <hip/hip_runtime.h>

// MHA forward, round 6.
// B=2, S=2048, D=1024, H=16, DH=64, scale=1/32 folded into exp2 constant.
//
// Pipeline (4 kernels):
//   0) prep:      cast x->bf16 (blocks 0..4095) + transpose W->Wt (4096..5119)
//   1) gemm_qkv:  grid (32,8,3). z=0: Q bf16 [b,h,s,64]; z=1: K same;
//                 z=2: Vp = Wtv @ xb^T -> bf16 [b,h,64,2048] sigma-permuted,
//                 written via LDS-transposed coalesced epilogue.
//   2) attn_q64:  causal flash attn, q-tile 64, balanced grid (66 tiles/CU)
//   3) gemm_out:  Ab @ Wt_o -> d_out fp32
//
// ws: xb 8@0 | Wt 8@8 | Qb 8@16 | Kb 8@24 | Vp 8@32 | Ab 8@40  (48MB)

#define AS1 __attribute__((address_space(1)))
#define AS3 __attribute__((address_space(3)))
#define EXPC2 0.04508422f  // (1/32) * log2(e)

typedef __attribute__((ext_vector_type(4))) float f32x4;
typedef __attribute__((ext_vector_type(8))) short bf16x8;

__device__ __forceinline__ void gload16(const void* g, void* l) {
  __builtin_amdgcn_global_load_lds((const AS1 unsigned int*)g,
                                   (AS3 unsigned int*)l, 16, 0, 0);
}
__device__ __forceinline__ unsigned short f2b(float f) {  // RNE fp32->bf16
  unsigned u = __float_as_uint(f);
  return (unsigned short)((u + 0x7FFFu + ((u >> 16) & 1u)) >> 16);
}
__device__ __forceinline__ float fexp2(float x) {
  float r;
  asm("v_exp_f32 %0, %1" : "=v"(r) : "v"(x));
  return r;
}
__device__ __forceinline__ unsigned cvtpk(float a, float b) {  // [a|b] bf16x2
  unsigned r;
  asm("v_cvt_pk_bf16_f32 %0, %1, %2" : "=v"(r) : "v"(a), "v"(b));
  return r;
}

// ---------------------------------------------------------------- prep ----
// blocks 0..4095: cast x fp32->bf16 (4 elem/thread).
// blocks 4096..5119: transpose W [K][N] fp32 -> Wt [N][K] bf16 (64x64 tiles).
__global__ __launch_bounds__(256) void prep(
    const float* __restrict__ x, const float* __restrict__ W0,
    const float* __restrict__ W1, const float* __restrict__ W2,
    const float* __restrict__ W3, unsigned short* __restrict__ xb,
    unsigned short* __restrict__ Wt) {
  __shared__ float T[64][65];
  const int tid = threadIdx.x;
  const int bid = blockIdx.x;
  if (bid < 4096) {
    const size_t i = (size_t)(bid * 256 + tid) * 4;
    float4 v = *(const float4*)&x[i];
    uint2 o;
    o.x = f2b(v.x) | ((unsigned)f2b(v.y) << 16);
    o.y = f2b(v.z) | ((unsigned)f2b(v.w) << 16);
    *(uint2*)&xb[i] = o;
    return;
  }
  const int idx = bid - 4096;
  const int kb = (idx & 15) * 64, nb = ((idx >> 4) & 15) * 64, z = idx >> 8;
  const float* W = (z == 0) ? W0 : (z == 1) ? W1 : (z == 2) ? W2 : W3;
  unsigned short* D = Wt + (size_t)z * 1024 * 1024;
#pragma unroll
  for (int p = 0; p < 4; ++p) {
    const int s = p * 256 + tid;
    const int r = s >> 4, c4 = s & 15;
    float4 v = *(const float4*)&W[(size_t)(kb + r) * 1024 + nb + c4 * 4];
    T[r][c4 * 4 + 0] = v.x;
    T[r][c4 * 4 + 1] = v.y;
    T[r][c4 * 4 + 2] = v.z;
    T[r][c4 * 4 + 3] = v.w;
  }
  __syncthreads();
#pragma unroll
  for (int p = 0; p < 4; ++p) {
    const int s = p * 256 + tid;
    const int n = s >> 4, k4 = s & 15;
    uint2 o;
    o.x = f2b(T[k4 * 4 + 0][n]) | ((unsigned)f2b(T[k4 * 4 + 1][n]) << 16);
    o.y = f2b(T[k4 * 4 + 2][n]) | ((unsigned)f2b(T[k4 * 4 + 3][n]) << 16);
    *(uint2*)&D[(size_t)(nb + n) * 1024 + kb + k4 * 4] = o;
  }
}

// ------------------------------------------------------------ gemm_qkv ----
// 128x128 tile, BK=32, 4 waves, mfma_f32_16x16x32_bf16.
// z=0: xb @ Wtq^T -> Qb bf16 [b,h,s,64]     (2B scatter, 32B runs)
// z=1: xb @ Wtk^T -> Kb bf16 [b,h,s,64]
// z=2: Wtv @ xb^T -> Vp bf16 [b,h,64,2048] sigma-permuted; LDS-transposed
//      coalesced writes (256B runs along s).
__global__ __launch_bounds__(256) void gemm_qkv(
    const unsigned short* __restrict__ xb, const unsigned short* __restrict__ Wtq,
    const unsigned short* __restrict__ Wtk, const unsigned short* __restrict__ Wtv,
    unsigned short* __restrict__ Qb, unsigned short* __restrict__ Kb,
    unsigned short* __restrict__ Vp) {
  __shared__ unsigned short smem[17408];  // As@0(4K), Bs@4096(4K); slab 128x136
  unsigned short* As = smem;
  unsigned short* Bs = smem + 4096;

  const int tid = threadIdx.x, lane = tid & 63, w = tid >> 6;
  const int z = blockIdx.z;
  const unsigned short* Ap;
  const unsigned short* Bp;
  int bm_, bn_;
  if (z == 2) {
    Ap = Wtv;
    Bp = xb;
    const int idx = blockIdx.x * 8 + blockIdx.y;  // 0..255
    bm_ = idx >> 5;                               // 0..7   (M=1024)
    bn_ = idx & 31;                               // 0..31  (N=4096)
  } else {
    Ap = xb;
    Bp = (z == 0) ? Wtq : Wtk;
    bm_ = blockIdx.x;  // 0..31
    bn_ = blockIdx.y;  // 0..7
  }
  const int wr = w >> 1, wc = w & 1;

  f32x4 acc[4][4];
#pragma unroll
  for (int m = 0; m < 4; ++m)
#pragma unroll
    for (int n = 0; n < 4; ++n) acc[m][n] = (f32x4)0.0f;

  const int srow = lane >> 2, scol = (lane & 3) * 8;
  const int fr = lane & 15, fk = (lane >> 4) * 8;

  for (int kc = 0; kc < 1024; kc += 32) {
    __syncthreads();
#pragma unroll
    for (int q = 0; q < 2; ++q) {
      const int r = w * 32 + q * 16;
      gload16(&Ap[(size_t)(bm_ * 128 + r + srow) * 1024 + kc + scol], &As[r * 32]);
      gload16(&Bp[(size_t)(bn_ * 128 + r + srow) * 1024 + kc + scol], &Bs[r * 32]);
    }
    __syncthreads();

    bf16x8 af[4], bf[4];
#pragma unroll
    for (int m = 0; m < 4; ++m)
      af[m] = *(const bf16x8*)&As[(wr * 64 + m * 16 + fr) * 32 + fk];
#pragma unroll
    for (int n = 0; n < 4; ++n)
      bf[n] = *(const bf16x8*)&Bs[(wc * 64 + n * 16 + fr) * 32 + fk];
#pragma unroll
    for (int m = 0; m < 4; ++m)
#pragma unroll
      for (int n = 0; n < 4; ++n)
        acc[m][n] = __builtin_amdgcn_mfma_f32_16x16x32_bf16(af[m], bf[n],
                                                            acc[m][n], 0, 0, 0);
  }

  const int fq = lane >> 4;
  if (z != 2) {
    unsigned short* Ob = (z == 0) ? Qb : Kb;
#pragma unroll
    for (int mf = 0; mf < 4; ++mf)
#pragma unroll
      for (int nf = 0; nf < 4; ++nf) {
        const int col = bn_ * 128 + wc * 64 + nf * 16 + fr;
#pragma unroll
        for (int rr = 0; rr < 4; ++rr) {
          const int m = bm_ * 128 + wr * 64 + mf * 16 + fq * 4 + rr;
          const int b = m >> 11, s = m & 2047;
          const int h = col >> 6, d = col & 63;
          Ob[((size_t)(b * 16 + h) * 2048 + s) * 64 + d] = f2b(acc[mf][nf][rr]);
        }
      }
    return;
  }

  // ---- z==2: V^T epilogue via LDS transpose slab [128 m][136] ----
  __syncthreads();  // all waves done reading As/Bs -> safe to alias slab
#pragma unroll
  for (int mf = 0; mf < 4; ++mf)
#pragma unroll
    for (int nf = 0; nf < 4; ++nf) {
      const int cl = wc * 64 + nf * 16 + fr;  // local col 0..127
      const int u = cl & 63, a = u >> 4;
      const int cperm =
          (cl & 64) | ((a >> 1) * 32 + ((u >> 2) & 3) * 8 + (a & 1) * 4 + (u & 3));
#pragma unroll
      for (int rr = 0; rr < 4; ++rr) {
        const int m = wr * 64 + mf * 16 + fq * 4 + rr;  // local row 0..127
        smem[m * 136 + cperm] = f2b(acc[mf][nf][rr]);
      }
    }
  __syncthreads();
  // coalesced out: row m -> (h,d); 256B contiguous along s per half-wave
  const int l5 = lane & 31;
  const size_t scol0 = (size_t)((bn_ * 128) & 2047);  // s offset (perm baked)
  const int bV = bn_ >> 4;
#pragma unroll
  for (int it = 0; it < 16; ++it) {
    const int rl = w * 32 + it * 2 + (lane >> 5);
    const int rowg = bm_ * 128 + rl;
    const int h = rowg >> 6, d = rowg & 63;
    uint2 v = *(const uint2*)&smem[rl * 136 + l5 * 4];
    *(uint2*)&Vp[((size_t)(bV * 16 + h) * 64 + d) * 2048 + scol0 + l5 * 4] = v;
  }
}

// ------------------------------------------------------------ gemm_out ----
// d_out[4096][1024] fp32 = Ab bf16 @ Wto^T.
__global__ __launch_bounds__(256) void gemm_out(
    const unsigned short* __restrict__ A, const unsigned short* __restrict__ Bt,
    float* __restrict__ Of) {
  __shared__ unsigned short As[128 * 32];
  __shared__ unsigned short Bs[128 * 32];
  const int tid = threadIdx.x, lane = tid & 63, w = tid >> 6;
  const int bm = blockIdx.x, bn = blockIdx.y;
  const int wr = w >> 1, wc = w & 1;

  f32x4 acc[4][4];
#pragma unroll
  for (int m = 0; m < 4; ++m)
#pragma unroll
    for (int n = 0; n < 4; ++n) acc[m][n] = (f32x4)0.0f;

  const int srow = lane >> 2, scol = (lane & 3) * 8;
  const int fr = lane & 15, fk = (lane >> 4) * 8;

  for (int kc = 0; kc < 1024; kc += 32) {
    __syncthreads();
#pragma unroll
    for (int q = 0; q < 2; ++q) {
      const int r = w * 32 + q * 16;
      gload16(&A[(size_t)(bm * 128 + r + srow) * 1024 + kc + scol], &As[r * 32]);
      gload16(&Bt[(size_t)(bn * 128 + r + srow) * 1024 + kc + scol], &Bs[r * 32]);
    }
    __syncthreads();

    bf16x8 af[4], bf[4];
#pragma unroll
    for (int m = 0; m < 4; ++m)
      af[m] = *(const bf16x8*)&As[(wr * 64 + m * 16 + fr) * 32 + fk];
#pragma unroll
    for (int n = 0; n < 4; ++n)
      bf[n] = *(const bf16x8*)&Bs[(wc * 64 + n * 16 + fr) * 32 + fk];
#pragma unroll
    for (int m = 0; m < 4; ++m)
#pragma unroll
      for (int n = 0; n < 4; ++n)
        acc[m][n] = __builtin_amdgcn_mfma_f32_16x16x32_bf16(af[m], bf[n],
                                                            acc[m][n], 0, 0, 0);
  }

  const int fq = lane >> 4;
#pragma unroll
  for (int mf = 0; mf < 4; ++mf)
#pragma unroll
    for (int nf = 0; nf < 4; ++nf) {
      const int col = bn * 128 + wc * 64 + nf * 16 + fr;
#pragma unroll
      for (int rr = 0; rr < 4; ++rr) {
        const int m = bm * 128 + wr * 64 + mf * 16 + fq * 4 + rr;
        Of[(size_t)m * 1024 + col] = acc[mf][nf][rr];
      }
    }
}

// ----------------------------------------------------------- attention ----
// q-tile 64 (wave owns 16 q-rows), kv-tile 64, dbuf LDS.
// Balanced grid: CU's 4 strided blocks have bq {2g, 2g+1, 31-2g, 30-2g}
// -> exactly 66 kv-tiles per CU.
// Swapped MFMA: S^T = K·Q^T, P in-register (sigma-matched Vp), O^T accum.
__global__ __launch_bounds__(256) void attn_q64(
    const unsigned short* __restrict__ Qb, const unsigned short* __restrict__ Kb,
    const unsigned short* __restrict__ Vp, unsigned short* __restrict__ Ab) {
  // 32KB: Ks dbuf @0/@4096, Vv dbuf @8192/@12288 (ushort idx); Ot aliases @0.
  __shared__ unsigned short smem[16384];

  const int tid = threadIdx.x, lane = tid & 63, w = tid >> 6;
  const int lo = lane & 15, hi = lane >> 4;

  const int id = blockIdx.x;
  const int qtr = id >> 8;        // 0..3
  const int g = (id >> 5) & 7;    // 0..7
  const int bh = id & 31;
  const int bq = (qtr == 0) ? 2 * g
               : (qtr == 1) ? 2 * g + 1
               : (qtr == 2) ? 31 - 2 * g
                            : 30 - 2 * g;
  const int qw = bq * 64 + w * 16;
  const size_t base = (size_t)bh * (2048 * 64);

  // Q as B-operand: col q = lo, rows d = ks*32 + hi*8 + j (raw; scale in exp)
  bf16x8 qf[2];
#pragma unroll
  for (int ks = 0; ks < 2; ++ks)
    qf[ks] =
        *(const bf16x8*)&Qb[base + (size_t)(qw + lo) * 64 + ks * 32 + hi * 8];

  f32x4 accO[4];  // O^T: row d = mf*16+hi*4+rr, col q = lo
#pragma unroll
  for (int mf = 0; mf < 4; ++mf) accO[mf] = (f32x4)0.0f;
  float mrow = -1e30f, lpart = 0.0f;

  const int ntile = bq + 1;
  const unsigned short* kgb = Kb + base;
  const unsigned short* vgb = Vp + base;
  const int lseg = w * 512;

#define STAGE(BUF, KBASE)                                                    \
  {                                                                          \
    const int kb_ = (KBASE);                                                 \
    _Pragma("unroll") for (int qq = 0; qq < 2; ++qq) {                       \
      const int slot = qq * 256 + tid;                                       \
      const int row = slot >> 3, ch = (slot & 7) ^ (row & 7);                \
      gload16(kgb + (size_t)(kb_ + row) * 64 + ch * 8,                       \
              &smem[(BUF)*4096 + qq * 2048 + lseg]);                         \
      gload16(vgb + (size_t)row * 2048 + kb_ + ch * 8,                       \
              &smem[8192 + (BUF)*4096 + qq * 2048 + lseg]);                  \
    }                                                                        \
  }

  STAGE(0, 0)
  int cur = 0;

  for (int t = 0; t < ntile; ++t) {
    __syncthreads();  // buf[cur] resident (compiler drains vmcnt at barrier)
    if (t + 1 < ntile) STAGE(cur ^ 1, (t + 1) * 64)

    const int kb = t * 64;
    const int x7 = lo & 7;
    // K as A-operand: row k = kf*16+lo, cols d = ks*32+hi*8+j
    bf16x8 ka[2][4];
#pragma unroll
    for (int ks = 0; ks < 2; ++ks) {
      const int ch = (ks * 4 + hi) ^ x7;
#pragma unroll
      for (int kf = 0; kf < 4; ++kf)
        ka[ks][kf] =
            *(const bf16x8*)&smem[cur * 4096 + (kf * 16 + lo) * 64 + ch * 8];
    }
    f32x4 st[4];  // S^T: row k = kf*16+hi*4+rr, col q = lo
#pragma unroll
    for (int kf = 0; kf < 4; ++kf) st[kf] = (f32x4)0.0f;
    __builtin_amdgcn_s_setprio(1);
#pragma unroll
    for (int ks = 0; ks < 2; ++ks)
#pragma unroll
      for (int kf = 0; kf < 4; ++kf)
        st[kf] = __builtin_amdgcn_mfma_f32_16x16x32_bf16(ka[ks][kf], qf[ks],
                                                         st[kf], 0, 0, 0);
    __builtin_amdgcn_s_setprio(0);

    // V^T as A-operand (issue early; lgkm hides under softmax)
    bf16x8 va[2][4];
#pragma unroll
    for (int ks = 0; ks < 2; ++ks) {
      const int ch = (ks * 4 + hi) ^ x7;
#pragma unroll
      for (int mf = 0; mf < 4; ++mf)
        va[ks][mf] = *(const bf16x8*)&smem[8192 + cur * 4096 +
                                           (mf * 16 + lo) * 64 + ch * 8];
    }

    // ---- softmax: lane holds k = kf*16 + hi*4 + rr for q = qw + lo ----
    float v[16];
#pragma unroll
    for (int kf = 0; kf < 4; ++kf)
#pragma unroll
      for (int rr = 0; rr < 4; ++rr) v[kf * 4 + rr] = st[kf][rr];
    if (kb + 63 > qw) {  // only the diagonal tile
      const int qg = qw + lo;
#pragma unroll
      for (int kf = 0; kf < 4; ++kf)
#pragma unroll
        for (int rr = 0; rr < 4; ++rr)
          if (kb + kf * 16 + hi * 4 + rr > qg) v[kf * 4 + rr] = -1e30f;
    }
    float mx = fmaxf(fmaxf(fmaxf(v[0], v[1]), fmaxf(v[2], v[3])),
                     fmaxf(fmaxf(v[4], v[5]), fmaxf(v[6], v[7])));
    mx = fmaxf(mx, fmaxf(fmaxf(fmaxf(v[8], v[9]), fmaxf(v[10], v[11])),
                         fmaxf(fmaxf(v[12], v[13]), fmaxf(v[14], v[15]))));
    mx = fmaxf(mx, __shfl_xor(mx, 16));
    mx = fmaxf(mx, __shfl_xor(mx, 32));
    // T13 defer-rescale: skip unless max grew by > 64 raw units (p <= 2^2.9)
    if (!__all(mx - mrow <= 64.0f)) {
      const float mnew = fmaxf(mrow, mx);
      const float al = fexp2((mrow - mnew) * EXPC2);
      mrow = mnew;
      lpart *= al;
#pragma unroll
      for (int mf = 0; mf < 4; ++mf)
#pragma unroll
        for (int rr = 0; rr < 4; ++rr) accO[mf][rr] *= al;
    }
    float p[16], rs = 0.0f;
#pragma unroll
    for (int i = 0; i < 16; ++i) {
      p[i] = fexp2((v[i] - mrow) * EXPC2);
      rs += p[i];
    }
    lpart += rs;

    // pack P^T B-operand: reg j of frag ks = p[ks*8+j] (sigma-matched Vp)
    bf16x8 pb[2];
#pragma unroll
    for (int ks = 0; ks < 2; ++ks) {
      uint4 u;
      u.x = cvtpk(p[ks * 8 + 0], p[ks * 8 + 1]);
      u.y = cvtpk(p[ks * 8 + 2], p[ks * 8 + 3]);
      u.z = cvtpk(p[ks * 8 + 4], p[ks * 8 + 5]);
      u.w = cvtpk(p[ks * 8 + 6], p[ks * 8 + 7]);
      pb[ks] = *(bf16x8*)&u;
    }

    __builtin_amdgcn_s_setprio(1);
#pragma unroll
    for (int ks = 0; ks < 2; ++ks)
#pragma unroll
      for (int mf = 0; mf < 4; ++mf)
        accO[mf] = __builtin_amdgcn_mfma_f32_16x16x32_bf16(va[ks][mf], pb[ks],
                                                           accO[mf], 0, 0, 0);
    __builtin_amdgcn_s_setprio(0);
    cur ^= 1;
  }

  __syncthreads();  // staging LDS dead everywhere -> safe to alias Ot

  // epilogue: denominator, normalize, transpose via wave-private slab
  float l = lpart;
  l += __shfl_xor(l, 16);
  l += __shfl_xor(l, 32);
  const float linv = 1.0f / l;
  unsigned short* ot = &smem[w * 1152];  // [16 q][72 d-pad]
#pragma unroll
  for (int mf = 0; mf < 4; ++mf) {
    uint2 u;
    u.x = cvtpk(accO[mf][0] * linv, accO[mf][1] * linv);
    u.y = cvtpk(accO[mf][2] * linv, accO[mf][3] * linv);
    *(uint2*)&ot[lo * 72 + mf * 16 + hi * 4] = u;
  }
  // wave-private slab: compiler orders ds_write -> ds_read via lgkmcnt
  const int b = bh >> 4, h = bh & 15;
  const int row = lane >> 2, cg = (lane & 3) * 16;
  uint4 o0 = *(const uint4*)&ot[row * 72 + cg];
  uint4 o1 = *(const uint4*)&ot[row * 72 + cg + 8];
  unsigned short* op = &Ab[(size_t)(b * 2048 + qw + row) * 1024 + h * 64 + cg];
  *(uint4*)op = o0;
  *(uint4*)(op + 8) = o1;
}

// -------------------------------------------------------------- launch ----
extern "C" void kernel_launch(void* const* d_in, const int* in_sizes, int n_in,
                              void* d_out, int out_size, void* d_ws,
                              size_t ws_size, hipStream_t stream) {
  (void)in_sizes; (void)n_in; (void)out_size; (void)ws_size;
  const float* x = (const float*)d_in[0];
  const float* Wq = (const float*)d_in[1];
  const float* Wk = (const float*)d_in[2];
  const float* Wv = (const float*)d_in[3];
  const float* Wo = (const float*)d_in[4];
  float* out = (float*)d_out;

  char* ws = (char*)d_ws;
  unsigned short* xb = (unsigned short*)(ws);                // 8MB
  unsigned short* Wt = (unsigned short*)(ws + (8u << 20));   // 4x2MB
  unsigned short* Qb = (unsigned short*)(ws + (16u << 20));  // 8MB
  unsigned short* Kb = (unsigned short*)(ws + (24u << 20));  // 8MB
  unsigned short* Vp = (unsigned short*)(ws + (32u << 20));  // 8MB
  unsigned short* Ab = (unsigned short*)(ws + (40u << 20));  // 8MB
  unsigned short* Wtq = Wt;
  unsigned short* Wtk = Wt + (1u << 20);
  unsigned short* Wtv = Wt + (2u << 20);
  unsigned short* Wto = Wt + (3u << 20);

  prep<<<dim3(5120), 256, 0, stream>>>(x, Wq, Wk, Wv, Wo, xb, Wt);
  gemm_qkv<<<dim3(32, 8, 3), 256, 0, stream>>>(xb, Wtq, Wtk, Wtv, Qb, Kb, Vp);
  attn_q64<<<dim3(1024), 256, 0, stream>>>(Qb, Kb, Vp, Ab);
  gemm_out<<<dim3(32, 8), 256, 0, stream>>>(Ab, Wto, out);
}

// Round 8
// 112.529 us; speedup vs baseline: 8.5557x; 1.0545x over previous
//
#include <hip/hip_runtime.h>

// MHA forward, round 8: round-7 structure with the Wto pointer bug fixed
// (element vs byte offset in the launcher — device code unchanged).
// B=2, S=2048, D=1024, H=16, DH=64, scale=1/32 folded into exp2 constant.
//
// Pipeline (4 kernels):
//   0) prep:       cast x->bf16 (blocks 0..4095) + transpose W->Wt (4096..5119)
//   1) gemm2ph<0>: xb[4096][1024] @ Wt[0:3072]^T, grid 768 linear, dbuf LDS.
//                  bn<8 -> Qb bf16 [b,h,s,64]; bn 8..15 -> Kb;
//                  bn 16..23 -> Vp bf16 [b,h,64,2048] sigma-permuted via
//                  LDS-transpose slab (stride 132).
//   2) attn_q64:   causal flash attn (round-6 proven)
//   3) gemm2ph<1>: Ab @ Wto^T -> d_out fp32, dbuf LDS.
//
// ws: xb 8@0 | Wt 8@8 | Qb 8@16 | Kb 8@24 | Vp 8@32 | Ab 8@40  (48MB)

#define AS1 __attribute__((address_space(1)))
#define AS3 __attribute__((address_space(3)))
#define EXPC2 0.04508422f  // (1/32) * log2(e)

typedef __attribute__((ext_vector_type(4))) float f32x4;
typedef __attribute__((ext_vector_type(8))) short bf16x8;

__device__ __forceinline__ void gload16(const void* g, void* l) {
  __builtin_amdgcn_global_load_lds((const AS1 unsigned int*)g,
                                   (AS3 unsigned int*)l, 16, 0, 0);
}
__device__ __forceinline__ unsigned short f2b(float f) {  // RNE fp32->bf16
  unsigned u = __float_as_uint(f);
  return (unsigned short)((u + 0x7FFFu + ((u >> 16) & 1u)) >> 16);
}
__device__ __forceinline__ float fexp2(float x) {
  float r;
  asm("v_exp_f32 %0, %1" : "=v"(r) : "v"(x));
  return r;
}
__device__ __forceinline__ unsigned cvtpk(float a, float b) {  // [a|b] bf16x2
  unsigned r;
  asm("v_cvt_pk_bf16_f32 %0, %1, %2" : "=v"(r) : "v"(a), "v"(b));
  return r;
}

// ---------------------------------------------------------------- prep ----
__global__ __launch_bounds__(256) void prep(
    const float* __restrict__ x, const float* __restrict__ W0,
    const float* __restrict__ W1, const float* __restrict__ W2,
    const float* __restrict__ W3, unsigned short* __restrict__ xb,
    unsigned short* __restrict__ Wt) {
  __shared__ float T[64][65];
  const int tid = threadIdx.x;
  const int bid = blockIdx.x;
  if (bid < 4096) {
    const size_t i = (size_t)(bid * 256 + tid) * 4;
    float4 v = *(const float4*)&x[i];
    uint2 o;
    o.x = f2b(v.x) | ((unsigned)f2b(v.y) << 16);
    o.y = f2b(v.z) | ((unsigned)f2b(v.w) << 16);
    *(uint2*)&xb[i] = o;
    return;
  }
  const int idx = bid - 4096;
  const int kb = (idx & 15) * 64, nb = ((idx >> 4) & 15) * 64, z = idx >> 8;
  const float* W = (z == 0) ? W0 : (z == 1) ? W1 : (z == 2) ? W2 : W3;
  unsigned short* D = Wt + (size_t)z * 1024 * 1024;
#pragma unroll
  for (int p = 0; p < 4; ++p) {
    const int s = p * 256 + tid;
    const int r = s >> 4, c4 = s & 15;
    float4 v = *(const float4*)&W[(size_t)(kb + r) * 1024 + nb + c4 * 4];
    T[r][c4 * 4 + 0] = v.x;
    T[r][c4 * 4 + 1] = v.y;
    T[r][c4 * 4 + 2] = v.z;
    T[r][c4 * 4 + 3] = v.w;
  }
  __syncthreads();
#pragma unroll
  for (int p = 0; p < 4; ++p) {
    const int s = p * 256 + tid;
    const int n = s >> 4, k4 = s & 15;
    uint2 o;
    o.x = f2b(T[k4 * 4 + 0][n]) | ((unsigned)f2b(T[k4 * 4 + 1][n]) << 16);
    o.y = f2b(T[k4 * 4 + 2][n]) | ((unsigned)f2b(T[k4 * 4 + 3][n]) << 16);
    *(uint2*)&D[(size_t)(nb + n) * 1024 + kb + k4 * 4] = o;
  }
}

// ----------------------------------------------------- 2-phase bf16 GEMM ----
// 128x128 tile, BK=32, 4 waves, double-buffered global_load_lds staging:
// barrier -> issue STAGE(t+1) -> compute(t); loads get a full compute phase
// in flight before the next barrier's vmcnt(0) drain.
// KIND 0: fused QKV. A=xb [4096][1024], B=Wt [3072][1024]. grid 768 linear,
//         bn = id%24, bm = id/24. Epilogue by bn: Q / K scatter, V slab.
// KIND 1: out GEMM. A=Ab [4096][1024], B=Wto [1024][1024]. grid 256 linear.
template <int KIND>
__global__ __launch_bounds__(256) void gemm2ph(
    const unsigned short* __restrict__ A, const unsigned short* __restrict__ B,
    unsigned short* __restrict__ Qb, unsigned short* __restrict__ Kb,
    unsigned short* __restrict__ Vp, float* __restrict__ Of) {
  // dbuf: buf0 A@0 B@4096, buf1 A@8192 B@12288 (ushort idx, 4096 each).
  // V slab [128][132] = 16896 ushorts aliases everything (after final barrier).
  __shared__ unsigned short smem[16896];

  const int tid = threadIdx.x, lane = tid & 63, w = tid >> 6;
  int bm, bn;
  if constexpr (KIND == 0) {
    bm = blockIdx.x / 24;
    bn = blockIdx.x % 24;
  } else {
    bm = blockIdx.x >> 3;
    bn = blockIdx.x & 7;
  }
  const int wr = w >> 1, wc = w & 1;

  f32x4 acc[4][4];
#pragma unroll
  for (int m = 0; m < 4; ++m)
#pragma unroll
    for (int n = 0; n < 4; ++n) acc[m][n] = (f32x4)0.0f;

  const int srow = lane >> 2, scol = (lane & 3) * 8;
  const int fr = lane & 15, fk = (lane >> 4) * 8;
  const size_t arow = (size_t)(bm * 128 + srow) * 1024 + scol;
  const size_t brow = (size_t)(bn * 128 + srow) * 1024 + scol;

#define GSTAGE(BUF, KC)                                                      \
  {                                                                          \
    _Pragma("unroll") for (int q = 0; q < 2; ++q) {                          \
      const int r = w * 32 + q * 16;                                         \
      gload16(&A[arow + (size_t)r * 1024 + (KC)],                            \
              &smem[(BUF) * 8192 + r * 32]);                                 \
      gload16(&B[brow + (size_t)r * 1024 + (KC)],                            \
              &smem[(BUF) * 8192 + 4096 + r * 32]);                          \
    }                                                                        \
  }

  GSTAGE(0, 0)
  int cur = 0;

  for (int t = 0; t < 32; ++t) {
    __syncthreads();  // drains vmcnt -> buf[cur] resident; buf[cur^1] readable
    if (t + 1 < 32) GSTAGE(cur ^ 1, (t + 1) * 32)

    bf16x8 af[4], bf[4];
#pragma unroll
    for (int m = 0; m < 4; ++m)
      af[m] = *(const bf16x8*)&smem[cur * 8192 + (wr * 64 + m * 16 + fr) * 32 + fk];
#pragma unroll
    for (int n = 0; n < 4; ++n)
      bf[n] = *(const bf16x8*)&smem[cur * 8192 + 4096 +
                                    (wc * 64 + n * 16 + fr) * 32 + fk];
#pragma unroll
    for (int m = 0; m < 4; ++m)
#pragma unroll
      for (int n = 0; n < 4; ++n)
        acc[m][n] = __builtin_amdgcn_mfma_f32_16x16x32_bf16(af[m], bf[n],
                                                            acc[m][n], 0, 0, 0);
    cur ^= 1;
  }

  const int fq = lane >> 4;
  if constexpr (KIND == 1) {
#pragma unroll
    for (int mf = 0; mf < 4; ++mf)
#pragma unroll
      for (int nf = 0; nf < 4; ++nf) {
        const int col = bn * 128 + wc * 64 + nf * 16 + fr;
#pragma unroll
        for (int rr = 0; rr < 4; ++rr) {
          const int m = bm * 128 + wr * 64 + mf * 16 + fq * 4 + rr;
          Of[(size_t)m * 1024 + col] = acc[mf][nf][rr];
        }
      }
    return;
  } else if (bn < 16) {
    // ---- Q / K scatter epilogue ----
    unsigned short* Ob = (bn < 8) ? Qb : Kb;
    const int cbase = (bn & 7) * 128;
#pragma unroll
    for (int mf = 0; mf < 4; ++mf)
#pragma unroll
      for (int nf = 0; nf < 4; ++nf) {
        const int col = cbase + wc * 64 + nf * 16 + fr;
        const int h = col >> 6, d = col & 63;
#pragma unroll
        for (int rr = 0; rr < 4; ++rr) {
          const int m = bm * 128 + wr * 64 + mf * 16 + fq * 4 + rr;
          const int b = m >> 11, s = m & 2047;
          Ob[((size_t)(b * 16 + h) * 2048 + s) * 64 + d] = f2b(acc[mf][nf][rr]);
        }
      }
    return;
  }

  // ---- V epilogue: LDS-transpose slab [cl 128][sperm 132] ----
  __syncthreads();  // all MFMAs/ds_reads done -> safe to alias slab
#pragma unroll
  for (int mf = 0; mf < 4; ++mf)
#pragma unroll
    for (int nf = 0; nf < 4; ++nf) {
      const int cl = wc * 64 + nf * 16 + fr;  // local (h,d) col 0..127
#pragma unroll
      for (int rr = 0; rr < 4; ++rr) {
        const int ml = wr * 64 + mf * 16 + fq * 4 + rr;  // local s 0..127
        const int u = ml & 63, a = u >> 4;
        const int sperm = (ml & 64) | ((a >> 1) * 32 + ((u >> 2) & 3) * 8 +
                                       (a & 1) * 4 + (u & 3));
        smem[cl * 132 + sperm] = f2b(acc[mf][nf][rr]);
      }
    }
  __syncthreads();
  // coalesced out: slab row rl -> (h,d); 256B runs along s
  const int l5 = lane & 31;
  const size_t sbase = (size_t)((bm * 128) & 2047);
  const int bV = bm >> 4;
#pragma unroll
  for (int it = 0; it < 16; ++it) {
    const int rl = w * 32 + it * 2 + (lane >> 5);
    const int rowg = (bn - 16) * 128 + rl;
    const int h = rowg >> 6, d = rowg & 63;
    uint2 v = *(const uint2*)&smem[rl * 132 + l5 * 4];
    *(uint2*)&Vp[((size_t)(bV * 16 + h) * 64 + d) * 2048 + sbase + l5 * 4] = v;
  }
#undef GSTAGE
}

// ----------------------------------------------------------- attention ----
// q-tile 64 (wave owns 16 q-rows), kv-tile 64, dbuf LDS. Balanced grid
// (66 kv-tiles/CU). Swapped MFMA: S^T = K·Q^T, P in-register (sigma-matched
// Vp), O^T accum.
__global__ __launch_bounds__(256) void attn_q64(
    const unsigned short* __restrict__ Qb, const unsigned short* __restrict__ Kb,
    const unsigned short* __restrict__ Vp, unsigned short* __restrict__ Ab) {
  __shared__ unsigned short smem[16384];

  const int tid = threadIdx.x, lane = tid & 63, w = tid >> 6;
  const int lo = lane & 15, hi = lane >> 4;

  const int id = blockIdx.x;
  const int qtr = id >> 8;      // 0..3
  const int g = (id >> 5) & 7;  // 0..7
  const int bh = id & 31;
  const int bq = (qtr == 0)   ? 2 * g
                 : (qtr == 1) ? 2 * g + 1
                 : (qtr == 2) ? 31 - 2 * g
                              : 30 - 2 * g;
  const int qw = bq * 64 + w * 16;
  const size_t base = (size_t)bh * (2048 * 64);

  bf16x8 qf[2];
#pragma unroll
  for (int ks = 0; ks < 2; ++ks)
    qf[ks] =
        *(const bf16x8*)&Qb[base + (size_t)(qw + lo) * 64 + ks * 32 + hi * 8];

  f32x4 accO[4];
#pragma unroll
  for (int mf = 0; mf < 4; ++mf) accO[mf] = (f32x4)0.0f;
  float mrow = -1e30f, lpart = 0.0f;

  const int ntile = bq + 1;
  const unsigned short* kgb = Kb + base;
  const unsigned short* vgb = Vp + base;
  const int lseg = w * 512;

#define STAGE(BUF, KBASE)                                                    \
  {                                                                          \
    const int kb_ = (KBASE);                                                 \
    _Pragma("unroll") for (int qq = 0; qq < 2; ++qq) {                       \
      const int slot = qq * 256 + tid;                                       \
      const int row = slot >> 3, ch = (slot & 7) ^ (row & 7);                \
      gload16(kgb + (size_t)(kb_ + row) * 64 + ch * 8,                       \
              &smem[(BUF)*4096 + qq * 2048 + lseg]);                         \
      gload16(vgb + (size_t)row * 2048 + kb_ + ch * 8,                       \
              &smem[8192 + (BUF)*4096 + qq * 2048 + lseg]);                  \
    }                                                                        \
  }

  STAGE(0, 0)
  int cur = 0;

  for (int t = 0; t < ntile; ++t) {
    __syncthreads();
    if (t + 1 < ntile) STAGE(cur ^ 1, (t + 1) * 64)

    const int kb = t * 64;
    const int x7 = lo & 7;
    bf16x8 ka[2][4];
#pragma unroll
    for (int ks = 0; ks < 2; ++ks) {
      const int ch = (ks * 4 + hi) ^ x7;
#pragma unroll
      for (int kf = 0; kf < 4; ++kf)
        ka[ks][kf] =
            *(const bf16x8*)&smem[cur * 4096 + (kf * 16 + lo) * 64 + ch * 8];
    }
    f32x4 st[4];
#pragma unroll
    for (int kf = 0; kf < 4; ++kf) st[kf] = (f32x4)0.0f;
    __builtin_amdgcn_s_setprio(1);
#pragma unroll
    for (int ks = 0; ks < 2; ++ks)
#pragma unroll
      for (int kf = 0; kf < 4; ++kf)
        st[kf] = __builtin_amdgcn_mfma_f32_16x16x32_bf16(ka[ks][kf], qf[ks],
                                                         st[kf], 0, 0, 0);
    __builtin_amdgcn_s_setprio(0);

    bf16x8 va[2][4];
#pragma unroll
    for (int ks = 0; ks < 2; ++ks) {
      const int ch = (ks * 4 + hi) ^ x7;
#pragma unroll
      for (int mf = 0; mf < 4; ++mf)
        va[ks][mf] = *(const bf16x8*)&smem[8192 + cur * 4096 +
                                           (mf * 16 + lo) * 64 + ch * 8];
    }

    float v[16];
#pragma unroll
    for (int kf = 0; kf < 4; ++kf)
#pragma unroll
      for (int rr = 0; rr < 4; ++rr) v[kf * 4 + rr] = st[kf][rr];
    if (kb + 63 > qw) {
      const int qg = qw + lo;
#pragma unroll
      for (int kf = 0; kf < 4; ++kf)
#pragma unroll
        for (int rr = 0; rr < 4; ++rr)
          if (kb + kf * 16 + hi * 4 + rr > qg) v[kf * 4 + rr] = -1e30f;
    }
    float mx = fmaxf(fmaxf(fmaxf(v[0], v[1]), fmaxf(v[2], v[3])),
                     fmaxf(fmaxf(v[4], v[5]), fmaxf(v[6], v[7])));
    mx = fmaxf(mx, fmaxf(fmaxf(fmaxf(v[8], v[9]), fmaxf(v[10], v[11])),
                         fmaxf(fmaxf(v[12], v[13]), fmaxf(v[14], v[15]))));
    mx = fmaxf(mx, __shfl_xor(mx, 16));
    mx = fmaxf(mx, __shfl_xor(mx, 32));
    if (!__all(mx - mrow <= 64.0f)) {
      const float mnew = fmaxf(mrow, mx);
      const float al = fexp2((mrow - mnew) * EXPC2);
      mrow = mnew;
      lpart *= al;
#pragma unroll
      for (int mf = 0; mf < 4; ++mf)
#pragma unroll
        for (int rr = 0; rr < 4; ++rr) accO[mf][rr] *= al;
    }
    float p[16], rs = 0.0f;
#pragma unroll
    for (int i = 0; i < 16; ++i) {
      p[i] = fexp2((v[i] - mrow) * EXPC2);
      rs += p[i];
    }
    lpart += rs;

    bf16x8 pb[2];
#pragma unroll
    for (int ks = 0; ks < 2; ++ks) {
      uint4 u;
      u.x = cvtpk(p[ks * 8 + 0], p[ks * 8 + 1]);
      u.y = cvtpk(p[ks * 8 + 2], p[ks * 8 + 3]);
      u.z = cvtpk(p[ks * 8 + 4], p[ks * 8 + 5]);
      u.w = cvtpk(p[ks * 8 + 6], p[ks * 8 + 7]);
      pb[ks] = *(bf16x8*)&u;
    }

    __builtin_amdgcn_s_setprio(1);
#pragma unroll
    for (int ks = 0; ks < 2; ++ks)
#pragma unroll
      for (int mf = 0; mf < 4; ++mf)
        accO[mf] = __builtin_amdgcn_mfma_f32_16x16x32_bf16(va[ks][mf], pb[ks],
                                                           accO[mf], 0, 0, 0);
    __builtin_amdgcn_s_setprio(0);
    cur ^= 1;
  }

  __syncthreads();

  float l = lpart;
  l += __shfl_xor(l, 16);
  l += __shfl_xor(l, 32);
  const float linv = 1.0f / l;
  unsigned short* ot = &smem[w * 1152];
#pragma unroll
  for (int mf = 0; mf < 4; ++mf) {
    uint2 u;
    u.x = cvtpk(accO[mf][0] * linv, accO[mf][1] * linv);
    u.y = cvtpk(accO[mf][2] * linv, accO[mf][3] * linv);
    *(uint2*)&ot[lo * 72 + mf * 16 + hi * 4] = u;
  }
  const int b = bh >> 4, h = bh & 15;
  const int row = lane >> 2, cg = (lane & 3) * 16;
  uint4 o0 = *(const uint4*)&ot[row * 72 + cg];
  uint4 o1 = *(const uint4*)&ot[row * 72 + cg + 8];
  unsigned short* op = &Ab[(size_t)(b * 2048 + qw + row) * 1024 + h * 64 + cg];
  *(uint4*)op = o0;
  *(uint4*)(op + 8) = o1;
}

// -------------------------------------------------------------- launch ----
extern "C" void kernel_launch(void* const* d_in, const int* in_sizes, int n_in,
                              void* d_out, int out_size, void* d_ws,
                              size_t ws_size, hipStream_t stream) {
  (void)in_sizes; (void)n_in; (void)out_size; (void)ws_size;
  const float* x = (const float*)d_in[0];
  const float* Wq = (const float*)d_in[1];
  const float* Wk = (const float*)d_in[2];
  const float* Wv = (const float*)d_in[3];
  const float* Wo = (const float*)d_in[4];
  float* out = (float*)d_out;

  char* ws = (char*)d_ws;
  unsigned short* xb = (unsigned short*)(ws);                // 8MB
  unsigned short* Wt = (unsigned short*)(ws + (8u << 20));   // 4x2MB (q,k,v,o)
  unsigned short* Qb = (unsigned short*)(ws + (16u << 20));  // 8MB
  unsigned short* Kb = (unsigned short*)(ws + (24u << 20));  // 8MB
  unsigned short* Vp = (unsigned short*)(ws + (32u << 20));  // 8MB
  unsigned short* Ab = (unsigned short*)(ws + (40u << 20));  // 8MB
  // ELEMENT offset: prep writes slab z at Wt + z*1024*1024 elements.
  unsigned short* Wto = Wt + (size_t)3 * 1024 * 1024;

  prep<<<dim3(5120), 256, 0, stream>>>(x, Wq, Wk, Wv, Wo, xb, Wt);
  gemm2ph<0><<<dim3(768), 256, 0, stream>>>(xb, Wt, Qb, Kb, Vp, nullptr);
  attn_q64<<<dim3(1024), 256, 0, stream>>>(Qb, Kb, Vp, Ab);
  gemm2ph<1><<<dim3(256), 256, 0, stream>>>(Ab, Wto, nullptr, nullptr, nullptr,
                                            out);
}

// Round 9
// 111.753 us; speedup vs baseline: 8.6151x; 1.0069x over previous
//
#include <hip/hip_runtime.h>

// MHA forward, round 9: GEMM LDS bank-conflict fix (row-pair packed, XOR-
// swizzled staging; rule #21 pre-swizzled global source + swizzled read).
// B=2, S=2048, D=1024, H=16, DH=64, scale=1/32 folded into exp2 constant.
//
// Pipeline (4 kernels):
//   0) prep:       cast x->bf16 + transpose W->Wt
//   1) gemm2ph<0>: fused QKV, grid 768, dbuf LDS, swizzled staging.
//   2) attn_q64:   causal flash attn (unchanged)
//   3) gemm2ph<1>: Ab @ Wto^T -> d_out fp32
//
// GEMM LDS tile layout (per 128x32-ushort matrix tile, 8KB):
//   logical (r 0..127, c 0..3 of 16B)  ->  phys row p=r>>1 (128B rows),
//   chunk pc = ((r&1)*4+c) ^ (p&7).  Quarter-wave read phases then hit each
//   bank-quad exactly 2x (free) instead of 8x (2.9x serialization).
//
// ws: xb 8@0 | Wt 8@8 | Qb 8@16 | Kb 8@24 | Vp 8@32 | Ab 8@40  (48MB)

#define AS1 __attribute__((address_space(1)))
#define AS3 __attribute__((address_space(3)))
#define EXPC2 0.04508422f  // (1/32) * log2(e)

typedef __attribute__((ext_vector_type(4))) float f32x4;
typedef __attribute__((ext_vector_type(8))) short bf16x8;

__device__ __forceinline__ void gload16(const void* g, void* l) {
  __builtin_amdgcn_global_load_lds((const AS1 unsigned int*)g,
                                   (AS3 unsigned int*)l, 16, 0, 0);
}
__device__ __forceinline__ unsigned short f2b(float f) {  // RNE fp32->bf16
  unsigned u = __float_as_uint(f);
  return (unsigned short)((u + 0x7FFFu + ((u >> 16) & 1u)) >> 16);
}
__device__ __forceinline__ float fexp2(float x) {
  float r;
  asm("v_exp_f32 %0, %1" : "=v"(r) : "v"(x));
  return r;
}
__device__ __forceinline__ unsigned cvtpk(float a, float b) {  // [a|b] bf16x2
  unsigned r;
  asm("v_cvt_pk_bf16_f32 %0, %1, %2" : "=v"(r) : "v"(a), "v"(b));
  return r;
}

// ---------------------------------------------------------------- prep ----
__global__ __launch_bounds__(256) void prep(
    const float* __restrict__ x, const float* __restrict__ W0,
    const float* __restrict__ W1, const float* __restrict__ W2,
    const float* __restrict__ W3, unsigned short* __restrict__ xb,
    unsigned short* __restrict__ Wt) {
  __shared__ float T[64][65];
  const int tid = threadIdx.x;
  const int bid = blockIdx.x;
  if (bid < 4096) {
    const size_t i = (size_t)(bid * 256 + tid) * 4;
    float4 v = *(const float4*)&x[i];
    uint2 o;
    o.x = f2b(v.x) | ((unsigned)f2b(v.y) << 16);
    o.y = f2b(v.z) | ((unsigned)f2b(v.w) << 16);
    *(uint2*)&xb[i] = o;
    return;
  }
  const int idx = bid - 4096;
  const int kb = (idx & 15) * 64, nb = ((idx >> 4) & 15) * 64, z = idx >> 8;
  const float* W = (z == 0) ? W0 : (z == 1) ? W1 : (z == 2) ? W2 : W3;
  unsigned short* D = Wt + (size_t)z * 1024 * 1024;
#pragma unroll
  for (int p = 0; p < 4; ++p) {
    const int s = p * 256 + tid;
    const int r = s >> 4, c4 = s & 15;
    float4 v = *(const float4*)&W[(size_t)(kb + r) * 1024 + nb + c4 * 4];
    T[r][c4 * 4 + 0] = v.x;
    T[r][c4 * 4 + 1] = v.y;
    T[r][c4 * 4 + 2] = v.z;
    T[r][c4 * 4 + 3] = v.w;
  }
  __syncthreads();
#pragma unroll
  for (int p = 0; p < 4; ++p) {
    const int s = p * 256 + tid;
    const int n = s >> 4, k4 = s & 15;
    uint2 o;
    o.x = f2b(T[k4 * 4 + 0][n]) | ((unsigned)f2b(T[k4 * 4 + 1][n]) << 16);
    o.y = f2b(T[k4 * 4 + 2][n]) | ((unsigned)f2b(T[k4 * 4 + 3][n]) << 16);
    *(uint2*)&D[(size_t)(nb + n) * 1024 + kb + k4 * 4] = o;
  }
}

// ----------------------------------------------------- 2-phase bf16 GEMM ----
// 128x128 tile, BK=32, 4 waves, dbuf global_load_lds staging, swizzled LDS.
// KIND 0: fused QKV. grid 768 linear, bn = id%24, bm = id/24.
// KIND 1: out GEMM. grid 256 linear.
template <int KIND>
__global__ __launch_bounds__(256) void gemm2ph(
    const unsigned short* __restrict__ A, const unsigned short* __restrict__ B,
    unsigned short* __restrict__ Qb, unsigned short* __restrict__ Kb,
    unsigned short* __restrict__ Vp, float* __restrict__ Of) {
  // dbuf: buf0 A@0 B@4096, buf1 A@8192 B@12288 (ushort idx, 4096 each).
  // V slab [128][132] = 16896 ushorts aliases everything (after final barrier).
  __shared__ unsigned short smem[16896];

  const int tid = threadIdx.x, lane = tid & 63, w = tid >> 6;
  int bm, bn;
  if constexpr (KIND == 0) {
    bm = blockIdx.x / 24;
    bn = blockIdx.x % 24;
  } else {
    bm = blockIdx.x >> 3;
    bn = blockIdx.x & 7;
  }
  const int wr = w >> 1, wc = w & 1;

  f32x4 acc[4][4];
#pragma unroll
  for (int m = 0; m < 4; ++m)
#pragma unroll
    for (int n = 0; n < 4; ++n) acc[m][n] = (f32x4)0.0f;

  // ---- staging source swizzle (write side of the involution) ----
  // lane l covers phys slot (p_local = l>>3, pc = l&7) of its 16-row segment;
  // u = pc ^ p_local; logical row offset = 2*(l>>3) + (u>>2), chunk = u&3.
  const int lu = (lane & 7) ^ (lane >> 3);
  const int srow2 = 2 * (lane >> 3) + (lu >> 2);
  const int scol2 = (lu & 3) * 8;
  const size_t arow = (size_t)(bm * 128 + srow2) * 1024 + scol2;
  const size_t brow = (size_t)(bn * 128 + srow2) * 1024 + scol2;

  // ---- fragment read swizzle (read side) ----
  // logical (row = base + m*16 + fr, chunk g): phys ushort addr =
  //   ((base>>1) + m*8 + (fr>>1))*64 + ((((fr&1)<<2)|g) ^ (fr>>1))*8
  const int fr = lane & 15, g = lane >> 4;
  const int fh = fr >> 1;                      // 0..7
  const int pcx = ((((fr & 1) << 2) | g) ^ fh) * 8;  // swizzled chunk offset

#define GSTAGE(BUF, KC)                                                      \
  {                                                                          \
    _Pragma("unroll") for (int q = 0; q < 2; ++q) {                          \
      const int r = w * 32 + q * 16;                                         \
      gload16(&A[arow + (size_t)r * 1024 + (KC)],                            \
              &smem[(BUF) * 8192 + r * 32]);                                 \
      gload16(&B[brow + (size_t)r * 1024 + (KC)],                            \
              &smem[(BUF) * 8192 + 4096 + r * 32]);                          \
    }                                                                        \
  }

  GSTAGE(0, 0)
  int cur = 0;

  for (int t = 0; t < 32; ++t) {
    __syncthreads();  // drains vmcnt -> buf[cur] resident
    if (t + 1 < 32) GSTAGE(cur ^ 1, (t + 1) * 32)

    bf16x8 af[4], bf[4];
#pragma unroll
    for (int m = 0; m < 4; ++m)
      af[m] = *(const bf16x8*)&smem[cur * 8192 + (wr * 32 + m * 8 + fh) * 64 +
                                    pcx];
#pragma unroll
    for (int n = 0; n < 4; ++n)
      bf[n] = *(const bf16x8*)&smem[cur * 8192 + 4096 +
                                    (wc * 32 + n * 8 + fh) * 64 + pcx];
#pragma unroll
    for (int m = 0; m < 4; ++m)
#pragma unroll
      for (int n = 0; n < 4; ++n)
        acc[m][n] = __builtin_amdgcn_mfma_f32_16x16x32_bf16(af[m], bf[n],
                                                            acc[m][n], 0, 0, 0);
    cur ^= 1;
  }

  const int fq = lane >> 4;
  if constexpr (KIND == 1) {
#pragma unroll
    for (int mf = 0; mf < 4; ++mf)
#pragma unroll
      for (int nf = 0; nf < 4; ++nf) {
        const int col = bn * 128 + wc * 64 + nf * 16 + fr;
#pragma unroll
        for (int rr = 0; rr < 4; ++rr) {
          const int m = bm * 128 + wr * 64 + mf * 16 + fq * 4 + rr;
          Of[(size_t)m * 1024 + col] = acc[mf][nf][rr];
        }
      }
    return;
  } else if (bn < 16) {
    // ---- Q / K scatter epilogue ----
    unsigned short* Ob = (bn < 8) ? Qb : Kb;
    const int cbase = (bn & 7) * 128;
#pragma unroll
    for (int mf = 0; mf < 4; ++mf)
#pragma unroll
      for (int nf = 0; nf < 4; ++nf) {
        const int col = cbase + wc * 64 + nf * 16 + fr;
        const int h = col >> 6, d = col & 63;
#pragma unroll
        for (int rr = 0; rr < 4; ++rr) {
          const int m = bm * 128 + wr * 64 + mf * 16 + fq * 4 + rr;
          const int b = m >> 11, s = m & 2047;
          Ob[((size_t)(b * 16 + h) * 2048 + s) * 64 + d] = f2b(acc[mf][nf][rr]);
        }
      }
    return;
  }

  // ---- V epilogue: LDS-transpose slab [cl 128][sperm 132] ----
  __syncthreads();  // all MFMAs/ds_reads done -> safe to alias slab
#pragma unroll
  for (int mf = 0; mf < 4; ++mf)
#pragma unroll
    for (int nf = 0; nf < 4; ++nf) {
      const int cl = wc * 64 + nf * 16 + fr;  // local (h,d) col 0..127
#pragma unroll
      for (int rr = 0; rr < 4; ++rr) {
        const int ml = wr * 64 + mf * 16 + fq * 4 + rr;  // local s 0..127
        const int u = ml & 63, a = u >> 4;
        const int sperm = (ml & 64) | ((a >> 1) * 32 + ((u >> 2) & 3) * 8 +
                                       (a & 1) * 4 + (u & 3));
        smem[cl * 132 + sperm] = f2b(acc[mf][nf][rr]);
      }
    }
  __syncthreads();
  // coalesced out: slab row rl -> (h,d); 256B runs along s
  const int l5 = lane & 31;
  const size_t sbase = (size_t)((bm * 128) & 2047);
  const int bV = bm >> 4;
#pragma unroll
  for (int it = 0; it < 16; ++it) {
    const int rl = w * 32 + it * 2 + (lane >> 5);
    const int rowg = (bn - 16) * 128 + rl;
    const int h = rowg >> 6, d = rowg & 63;
    uint2 v = *(const uint2*)&smem[rl * 132 + l5 * 4];
    *(uint2*)&Vp[((size_t)(bV * 16 + h) * 64 + d) * 2048 + sbase + l5 * 4] = v;
  }
#undef GSTAGE
}

// ----------------------------------------------------------- attention ----
// q-tile 64 (wave owns 16 q-rows), kv-tile 64, dbuf LDS. Balanced grid
// (66 kv-tiles/CU). Swapped MFMA: S^T = K·Q^T, P in-register (sigma-matched
// Vp), O^T accum. Unchanged (already ~conflict-free: 128B rows + XOR).
__global__ __launch_bounds__(256) void attn_q64(
    const unsigned short* __restrict__ Qb, const unsigned short* __restrict__ Kb,
    const unsigned short* __restrict__ Vp, unsigned short* __restrict__ Ab) {
  __shared__ unsigned short smem[16384];

  const int tid = threadIdx.x, lane = tid & 63, w = tid >> 6;
  const int lo = lane & 15, hi = lane >> 4;

  const int id = blockIdx.x;
  const int qtr = id >> 8;      // 0..3
  const int g = (id >> 5) & 7;  // 0..7
  const int bh = id & 31;
  const int bq = (qtr == 0)   ? 2 * g
                 : (qtr == 1) ? 2 * g + 1
                 : (qtr == 2) ? 31 - 2 * g
                              : 30 - 2 * g;
  const int qw = bq * 64 + w * 16;
  const size_t base = (size_t)bh * (2048 * 64);

  bf16x8 qf[2];
#pragma unroll
  for (int ks = 0; ks < 2; ++ks)
    qf[ks] =
        *(const bf16x8*)&Qb[base + (size_t)(qw + lo) * 64 + ks * 32 + hi * 8];

  f32x4 accO[4];
#pragma unroll
  for (int mf = 0; mf < 4; ++mf) accO[mf] = (f32x4)0.0f;
  float mrow = -1e30f, lpart = 0.0f;

  const int ntile = bq + 1;
  const unsigned short* kgb = Kb + base;
  const unsigned short* vgb = Vp + base;
  const int lseg = w * 512;

#define STAGE(BUF, KBASE)                                                    \
  {                                                                          \
    const int kb_ = (KBASE);                                                 \
    _Pragma("unroll") for (int qq = 0; qq < 2; ++qq) {                       \
      const int slot = qq * 256 + tid;                                       \
      const int row = slot >> 3, ch = (slot & 7) ^ (row & 7);                \
      gload16(kgb + (size_t)(kb_ + row) * 64 + ch * 8,                       \
              &smem[(BUF)*4096 + qq * 2048 + lseg]);                         \
      gload16(vgb + (size_t)row * 2048 + kb_ + ch * 8,                       \
              &smem[8192 + (BUF)*4096 + qq * 2048 + lseg]);                  \
    }                                                                        \
  }

  STAGE(0, 0)
  int cur = 0;

  for (int t = 0; t < ntile; ++t) {
    __syncthreads();
    if (t + 1 < ntile) STAGE(cur ^ 1, (t + 1) * 64)

    const int kb = t * 64;
    const int x7 = lo & 7;
    bf16x8 ka[2][4];
#pragma unroll
    for (int ks = 0; ks < 2; ++ks) {
      const int ch = (ks * 4 + hi) ^ x7;
#pragma unroll
      for (int kf = 0; kf < 4; ++kf)
        ka[ks][kf] =
            *(const bf16x8*)&smem[cur * 4096 + (kf * 16 + lo) * 64 + ch * 8];
    }
    f32x4 st[4];
#pragma unroll
    for (int kf = 0; kf < 4; ++kf) st[kf] = (f32x4)0.0f;
    __builtin_amdgcn_s_setprio(1);
#pragma unroll
    for (int ks = 0; ks < 2; ++ks)
#pragma unroll
      for (int kf = 0; kf < 4; ++kf)
        st[kf] = __builtin_amdgcn_mfma_f32_16x16x32_bf16(ka[ks][kf], qf[ks],
                                                         st[kf], 0, 0, 0);
    __builtin_amdgcn_s_setprio(0);

    bf16x8 va[2][4];
#pragma unroll
    for (int ks = 0; ks < 2; ++ks) {
      const int ch = (ks * 4 + hi) ^ x7;
#pragma unroll
      for (int mf = 0; mf < 4; ++mf)
        va[ks][mf] = *(const bf16x8*)&smem[8192 + cur * 4096 +
                                           (mf * 16 + lo) * 64 + ch * 8];
    }

    float v[16];
#pragma unroll
    for (int kf = 0; kf < 4; ++kf)
#pragma unroll
      for (int rr = 0; rr < 4; ++rr) v[kf * 4 + rr] = st[kf][rr];
    if (kb + 63 > qw) {
      const int qg = qw + lo;
#pragma unroll
      for (int kf = 0; kf < 4; ++kf)
#pragma unroll
        for (int rr = 0; rr < 4; ++rr)
          if (kb + kf * 16 + hi * 4 + rr > qg) v[kf * 4 + rr] = -1e30f;
    }
    float mx = fmaxf(fmaxf(fmaxf(v[0], v[1]), fmaxf(v[2], v[3])),
                     fmaxf(fmaxf(v[4], v[5]), fmaxf(v[6], v[7])));
    mx = fmaxf(mx, fmaxf(fmaxf(fmaxf(v[8], v[9]), fmaxf(v[10], v[11])),
                         fmaxf(fmaxf(v[12], v[13]), fmaxf(v[14], v[15]))));
    mx = fmaxf(mx, __shfl_xor(mx, 16));
    mx = fmaxf(mx, __shfl_xor(mx, 32));
    if (!__all(mx - mrow <= 64.0f)) {
      const float mnew = fmaxf(mrow, mx);
      const float al = fexp2((mrow - mnew) * EXPC2);
      mrow = mnew;
      lpart *= al;
#pragma unroll
      for (int mf = 0; mf < 4; ++mf)
#pragma unroll
        for (int rr = 0; rr < 4; ++rr) accO[mf][rr] *= al;
    }
    float p[16], rs = 0.0f;
#pragma unroll
    for (int i = 0; i < 16; ++i) {
      p[i] = fexp2((v[i] - mrow) * EXPC2);
      rs += p[i];
    }
    lpart += rs;

    bf16x8 pb[2];
#pragma unroll
    for (int ks = 0; ks < 2; ++ks) {
      uint4 u;
      u.x = cvtpk(p[ks * 8 + 0], p[ks * 8 + 1]);
      u.y = cvtpk(p[ks * 8 + 2], p[ks * 8 + 3]);
      u.z = cvtpk(p[ks * 8 + 4], p[ks * 8 + 5]);
      u.w = cvtpk(p[ks * 8 + 6], p[ks * 8 + 7]);
      pb[ks] = *(bf16x8*)&u;
    }

    __builtin_amdgcn_s_setprio(1);
#pragma unroll
    for (int ks = 0; ks < 2; ++ks)
#pragma unroll
      for (int mf = 0; mf < 4; ++mf)
        accO[mf] = __builtin_amdgcn_mfma_f32_16x16x32_bf16(va[ks][mf], pb[ks],
                                                           accO[mf], 0, 0, 0);
    __builtin_amdgcn_s_setprio(0);
    cur ^= 1;
  }

  __syncthreads();

  float l = lpart;
  l += __shfl_xor(l, 16);
  l += __shfl_xor(l, 32);
  const float linv = 1.0f / l;
  unsigned short* ot = &smem[w * 1152];
#pragma unroll
  for (int mf = 0; mf < 4; ++mf) {
    uint2 u;
    u.x = cvtpk(accO[mf][0] * linv, accO[mf][1] * linv);
    u.y = cvtpk(accO[mf][2] * linv, accO[mf][3] * linv);
    *(uint2*)&ot[lo * 72 + mf * 16 + hi * 4] = u;
  }
  const int b = bh >> 4, h = bh & 15;
  const int row = lane >> 2, cg = (lane & 3) * 16;
  uint4 o0 = *(const uint4*)&ot[row * 72 + cg];
  uint4 o1 = *(const uint4*)&ot[row * 72 + cg + 8];
  unsigned short* op = &Ab[(size_t)(b * 2048 + qw + row) * 1024 + h * 64 + cg];
  *(uint4*)op = o0;
  *(uint4*)(op + 8) = o1;
}

// -------------------------------------------------------------- launch ----
extern "C" void kernel_launch(void* const* d_in, const int* in_sizes, int n_in,
                              void* d_out, int out_size, void* d_ws,
                              size_t ws_size, hipStream_t stream) {
  (void)in_sizes; (void)n_in; (void)out_size; (void)ws_size;
  const float* x = (const float*)d_in[0];
  const float* Wq = (const float*)d_in[1];
  const float* Wk = (const float*)d_in[2];
  const float* Wv = (const float*)d_in[3];
  const float* Wo = (const float*)d_in[4];
  float* out = (float*)d_out;

  char* ws = (char*)d_ws;
  unsigned short* xb = (unsigned short*)(ws);                // 8MB
  unsigned short* Wt = (unsigned short*)(ws + (8u << 20));   // 4x2MB (q,k,v,o)
  unsigned short* Qb = (unsigned short*)(ws + (16u << 20));  // 8MB
  unsigned short* Kb = (unsigned short*)(ws + (24u << 20));  // 8MB
  unsigned short* Vp = (unsigned short*)(ws + (32u << 20));  // 8MB
  unsigned short* Ab = (unsigned short*)(ws + (40u << 20));  // 8MB
  // ELEMENT offset: prep writes slab z at Wt + z*1024*1024 elements.
  unsigned short* Wto = Wt + (size_t)3 * 1024 * 1024;

  prep<<<dim3(5120), 256, 0, stream>>>(x, Wq, Wk, Wv, Wo, xb, Wt);
  gemm2ph<0><<<dim3(768), 256, 0, stream>>>(xb, Wt, Qb, Kb, Vp, nullptr);
  attn_q64<<<dim3(1024), 256, 0, stream>>>(Qb, Kb, Vp, Ab);
  gemm2ph<1><<<dim3(256), 256, 0, stream>>>(Ab, Wto, nullptr, nullptr, nullptr,
                                            out);
}